// Round 15
// baseline (617.676 us; speedup 1.0000x reference)
//
#include <hip/hip_runtime.h>

typedef float fvec4 __attribute__((ext_vector_type(4)));

#define NN 65536      // total nodes per side (B*NPG)
#define EE 1048576    // edges per side (B*NPG*DEG)
#define BB 128
#define NPG 512
#define EPG 8192      // edges per graph (NPG*DEG)

// ---------------- one block per (side, graph), 1024 threads = 2 per node ----------------
// thread t: half = t>>9 (feature half), v = t&511 (rank); node = nodeOf[v] (degree-sorted).
// lo half owns features [0:F/2), hi half [F/2:F) of every layer; msg buffers bufLo/bufHi.
// Partial-sum exchanges for y1=h0*W1 and y2=h1*W2 go through swizzled scratch in the
// upper 32KB of each buffer (disjoint from msg rows).
__global__ __launch_bounds__(1024)
void k_all(const float* __restrict__ x_i, const float* __restrict__ x_j,
           const float* __restrict__ gw0, const float* __restrict__ gb0,
           const float* __restrict__ gw1, const float* __restrict__ gb1,
           const float* __restrict__ gw2, const float* __restrict__ gb2,
           const int* __restrict__ ei, const int* __restrict__ ej,
           float* __restrict__ hs0, float* __restrict__ hs1, float* __restrict__ hs2) {
  __shared__ fvec4 bufLo[NPG * 8];        // 64 KB: lo msg rows (32 f32/node max)
  __shared__ fvec4 bufHi[NPG * 8];        // 64 KB: hi msg rows
  __shared__ unsigned short sids[EPG];    // 16 KB: CSR src ids (u16)
  __shared__ int cnt[NPG];
  __shared__ int posb[NPG];
  __shared__ int nodeOf[NPG];
  __shared__ int bins[64];
  __shared__ int binpos[64];
  __shared__ int wsum[8];
  unsigned short* const dsts = reinterpret_cast<unsigned short*>(bufLo);  // prep-only

  const int side = blockIdx.x >> 7;
  const int g = blockIdx.x & 127;
  const float* __restrict__ x = side ? x_j : x_i;
  const int* __restrict__ eidx = side ? ej : ei;
  const int t = threadIdx.x;
  const int half = t >> 9;
  const int v = t & 511;
  const int base = g * NPG;
  const int ebase = g * EPG;

  // ---- degree count (all 1024 threads) ----
  if (t < NPG) cnt[t] = 0;
  if (t < 64) bins[t] = 0;
  __syncthreads();
  for (int k = t; k < EPG; k += 1024) {
    int d = eidx[EE + ebase + k] - base;
    dsts[k] = (unsigned short)d;
    atomicAdd(&cnt[d], 1);
  }
  __syncthreads();

  // ---- scan + degree histogram (first 512 threads = waves 0-7) ----
  int count = 0, xa = 0, deg = 0;
  if (t < NPG) {
    count = cnt[t];
    deg = count > 63 ? 63 : count;
    atomicAdd(&bins[deg], 1);
    xa = count;
    const int lane = t & 63;
#pragma unroll
    for (int d = 1; d < 64; d <<= 1) {
      int y = __shfl_up(xa, d, 64);
      if (lane >= d) xa += y;
    }
    if (lane == 63) wsum[t >> 6] = xa;
  }
  __syncthreads();
  if (t < 64) {
    if (t == 0) {
      int a = 0;
#pragma unroll
      for (int i = 0; i < 8; ++i) { int tv = wsum[i]; wsum[i] = a; a += tv; }
    }
    int c = bins[t];
    int xb = c;
#pragma unroll
    for (int d = 1; d < 64; d <<= 1) {
      int y = __shfl_up(xb, d, 64);
      if (t >= d) xb += y;
    }
    binpos[t] = xb - c;
  }
  __syncthreads();
  if (t < NPG) {
    posb[t] = xa - count + wsum[t >> 6];
    int rank = atomicAdd(&binpos[deg], 1);
    nodeOf[rank] = t;
  }
  __syncthreads();

  // ---- CSR fill (all 1024 threads) ----
  for (int k = t; k < EPG; k += 1024) {
    int lv = eidx[ebase + k] - base;
    int p = atomicAdd(&posb[dsts[k]], 1);
    sids[p] = (unsigned short)lv;
  }
  __syncthreads();

  // ---- per-thread node assignment (wave-uniform degrees) ----
  const int node = nodeOf[v];
  const int ncount = cnt[node];
  const int nstart = posb[node] - ncount;
  const float inv_v = rsqrtf((float)ncount + 1.0f);
  constexpr int srows[20] = {25, 26, 76, 77, 127, 128, 178, 179, 229, 230,
                             281, 282, 332, 333, 383, 384, 434, 435, 485, 486};
  int slot = -1;
#pragma unroll
  for (int i = 0; i < 20; ++i)
    if (node == srows[i]) slot = i;
  const int hb = (side * BB + g) * 20;
  fvec4* const mybuf = half ? bufHi : bufLo;
  fvec4* const scrSelf = mybuf + 2048;                      // upper 32 KB
  fvec4* const scrOther = (half ? bufLo : bufHi) + 2048;

  // ---- L0 GEMM: y0_half = x_row * W0[:, half*32 : half*32+32] ----
  fvec4 a0[8];
#pragma unroll
  for (int q = 0; q < 8; ++q) a0[q] = fvec4{0.f, 0.f, 0.f, 0.f};
  {
    const fvec4* xv = reinterpret_cast<const fvec4*>(x + (size_t)(base + node) * 64);
    const float* w0h = gw0 + half * 32;
#pragma unroll 1
    for (int k16 = 0; k16 < 4; ++k16) {
      fvec4 xq[4];
#pragma unroll
      for (int u = 0; u < 4; ++u) xq[u] = xv[4 * k16 + u];
#pragma unroll
      for (int u = 0; u < 4; ++u) {
#pragma unroll
        for (int j = 0; j < 4; ++j) {
          const float xk = xq[u][j];
          const fvec4* wr = reinterpret_cast<const fvec4*>(w0h + (size_t)(16 * k16 + 4 * u + j) * 64);
#pragma unroll
          for (int q = 0; q < 8; ++q) a0[q] += xk * wr[q];
        }
      }
    }
  }

  // ---- L0 publish (32 f32, own line, slot (q+node)&7) + self init ----
  fvec4 s[8];
  {
    const int bse = node << 3;
#pragma unroll
    for (int q = 0; q < 8; ++q) {
      fvec4 mv = a0[q] * inv_v;
      mybuf[bse | ((q + node) & 7)] = mv;
      s[q] = mv;
    }
  }
  __syncthreads();

  // ---- L0 gather (32 feats/thread) ----
  {
    const int end = nstart + ncount;
    for (int e = nstart; e < end; ++e) {
      const int n = sids[e];
      const int bse = n << 3;
#pragma unroll
      for (int q = 0; q < 8; ++q) s[q] += mybuf[bse | ((q + n) & 7)];
    }
  }

  // ---- L0 epilogue: h0_half = relu(s*inv + b); fold p1 = h0_half * W1[half rows] ----
  fvec4 p1[8];
#pragma unroll
  for (int q = 0; q < 8; ++q) p1[q] = fvec4{0.f, 0.f, 0.f, 0.f};
  {
    const fvec4* gb0v = reinterpret_cast<const fvec4*>(gb0 + half * 32);
    float* hp = hs0 + ((size_t)hb + slot) * 64 + half * 32;
#pragma unroll
    for (int q = 0; q < 8; ++q) {
      fvec4 o = s[q] * inv_v + gb0v[q];
#pragma unroll
      for (int j = 0; j < 4; ++j) o[j] = fmaxf(o[j], 0.f);
      if (slot >= 0) reinterpret_cast<fvec4*>(hp)[q] = o;
#pragma unroll
      for (int j = 0; j < 4; ++j) {
        const float hf = o[j];
        const fvec4* wr = reinterpret_cast<const fvec4*>(gw1 + (size_t)(half * 32 + q * 4 + j) * 32);
#pragma unroll
        for (int p = 0; p < 8; ++p) p1[p] += hf * wr[p];
      }
    }
  }
  __syncthreads();  // all L0 gather reads complete

  // ---- y1 partial exchange: lo stores outs[16:32), hi stores outs[0:16) ----
  {
    const int so = half ? 0 : 4;
#pragma unroll
    for (int q = 0; q < 4; ++q) scrSelf[(node << 2) | ((q + node) & 3)] = p1[so + q];
  }
  __syncthreads();
  // ---- combine + L1 publish (16 f32, 2 rows/line) ----
  fvec4 s1[4];
  {
    const int ko = half ? 4 : 0;
    const int line = node >> 1;
    const int m = ((node & 1) << 2) + (line & 7);
    const int bse = line << 3;
#pragma unroll
    for (int q = 0; q < 4; ++q) {
      fvec4 y = p1[ko + q] + scrOther[(node << 2) | ((q + node) & 3)];
      fvec4 mv = y * inv_v;
      mybuf[bse | ((q + m) & 7)] = mv;
      s1[q] = mv;
    }
  }
  __syncthreads();

  // ---- L1 gather (16 feats/thread) ----
  {
    const int end = nstart + ncount;
    for (int e = nstart; e < end; ++e) {
      const int n = sids[e];
      const int line = n >> 1;
      const int m = ((n & 1) << 2) + (line & 7);
      const int bse = line << 3;
#pragma unroll
      for (int q = 0; q < 4; ++q) s1[q] += mybuf[bse | ((q + m) & 7)];
    }
  }

  // ---- L1 epilogue: h1_half = relu(...); fold p2 = h1_half * W2[half rows] ----
  fvec4 p2[4];
#pragma unroll
  for (int q = 0; q < 4; ++q) p2[q] = fvec4{0.f, 0.f, 0.f, 0.f};
  {
    const fvec4* gb1v = reinterpret_cast<const fvec4*>(gb1 + half * 16);
    float* hp = hs1 + ((size_t)hb + slot) * 32 + half * 16;
#pragma unroll
    for (int q = 0; q < 4; ++q) {
      fvec4 o = s1[q] * inv_v + gb1v[q];
#pragma unroll
      for (int j = 0; j < 4; ++j) o[j] = fmaxf(o[j], 0.f);
      if (slot >= 0) reinterpret_cast<fvec4*>(hp)[q] = o;
#pragma unroll
      for (int j = 0; j < 4; ++j) {
        const float hf = o[j];
        const fvec4* wr = reinterpret_cast<const fvec4*>(gw2 + (size_t)(half * 16 + q * 4 + j) * 16);
#pragma unroll
        for (int p = 0; p < 4; ++p) p2[p] += hf * wr[p];
      }
    }
  }
  __syncthreads();  // all L1 gather reads complete

  // ---- y2 partial exchange: lo stores outs[8:16), hi stores outs[0:8) ----
  {
    const int so = half ? 0 : 2;
#pragma unroll
    for (int q = 0; q < 2; ++q) scrSelf[(node << 2) | ((q + node) & 3)] = p2[so + q];
  }
  __syncthreads();
  // ---- combine + L2 publish (8 f32, 4 rows/line) ----
  fvec4 s2[2];
  {
    const int ko = half ? 2 : 0;
    const int line = node >> 2;
    const int m = ((node & 3) << 1) + (line & 7);
    const int bse = line << 3;
#pragma unroll
    for (int q = 0; q < 2; ++q) {
      fvec4 y = p2[ko + q] + scrOther[(node << 2) | ((q + node) & 3)];
      fvec4 mv = y * inv_v;
      mybuf[bse | ((q + m) & 7)] = mv;
      s2[q] = mv;
    }
  }
  __syncthreads();

  // ---- L2 gather: only sampled rows ----
  if (slot >= 0) {
    const int end = nstart + ncount;
    for (int e = nstart; e < end; ++e) {
      const int n = sids[e];
      const int line = n >> 2;
      const int m = ((n & 3) << 1) + (line & 7);
      const int bse = line << 3;
#pragma unroll
      for (int q = 0; q < 2; ++q) s2[q] += mybuf[bse | ((q + m) & 7)];
    }
    const fvec4* gb2v = reinterpret_cast<const fvec4*>(gb2 + half * 8);
    fvec4* hp = reinterpret_cast<fvec4*>(hs2 + ((size_t)hb + slot) * 16 + half * 8);
#pragma unroll
    for (int q = 0; q < 2; ++q) hp[q] = s2[q] * inv_v + gb2v[q];
  }
}

// ---------------- head: sampled sim -> bilinear 10x10 -> conv3x3(1->8) -> MLP -> sigmoid ----------------
__global__ __launch_bounds__(256) void k_head(const float* __restrict__ hs0, const float* __restrict__ hs1,
                                              const float* __restrict__ hs2,
                                              const float* __restrict__ cw0, const float* __restrict__ cb0,
                                              const float* __restrict__ cw1, const float* __restrict__ cb1,
                                              const float* __restrict__ cw2, const float* __restrict__ cb2,
                                              const float* __restrict__ mw0, const float* __restrict__ mb0,
                                              const float* __restrict__ mw1, const float* __restrict__ mb1,
                                              const float* __restrict__ mw2, const float* __restrict__ mb2,
                                              const float* __restrict__ mw3, const float* __restrict__ mb3,
                                              const float* __restrict__ mw4, const float* __restrict__ mb4,
                                              const float* __restrict__ sw, const float* __restrict__ sb,
                                              float* __restrict__ out) {
  __shared__ float hi[2240];  // 20*64 + 20*32 + 20*16
  __shared__ float hj[2240];
  __shared__ float sim[400];
  __shared__ float simr[100];
  __shared__ float feat[2400];
  __shared__ float red[256];
  __shared__ float mbuf[60];
  const int b = blockIdx.x, t = threadIdx.x;

  for (int k = t; k < 1280; k += 256) {
    hi[k] = hs0[(size_t)(0 * BB + b) * 1280 + k];
    hj[k] = hs0[(size_t)(1 * BB + b) * 1280 + k];
  }
  for (int k = t; k < 640; k += 256) {
    hi[1280 + k] = hs1[(size_t)(0 * BB + b) * 640 + k];
    hj[1280 + k] = hs1[(size_t)(1 * BB + b) * 640 + k];
  }
  for (int k = t; k < 320; k += 256) {
    hi[1920 + k] = hs2[(size_t)(0 * BB + b) * 320 + k];
    hj[1920 + k] = hs2[(size_t)(1 * BB + b) * 320 + k];
  }
  __syncthreads();

  const int Fs[3] = {64, 32, 16};
  const int HOFF[3] = {0, 1280, 1920};
  const float* CW[3] = {cw0, cw1, cw2};
  const float* CB[3] = {cb0, cb1, cb2};

  for (int li = 0; li < 3; ++li) {
    const int F = Fs[li];
    const float* Hi = hi + HOFF[li];
    const float* Hj = hj + HOFF[li];
    for (int p = t; p < 400; p += 256) {
      int r = p / 20, cq = p % 20;
      float a = 0.0f;
      for (int d = 0; d < F; ++d) a += Hi[r * F + d] * Hj[cq * F + d];
      sim[p] = a;
    }
    __syncthreads();
    if (t < 100) {
      int oy = t / 10, ox = t % 10;
      float cy = (oy + 0.5f) * (512.0f / 10.0f) - 0.5f;
      float cx = (ox + 0.5f) * (512.0f / 10.0f) - 0.5f;
      float fy = cy - floorf(cy);
      float fx = cx - floorf(cx);
      int r0 = 2 * oy, c0 = 2 * ox;
      float s00 = sim[r0 * 20 + c0], s01 = sim[r0 * 20 + c0 + 1];
      float s10 = sim[(r0 + 1) * 20 + c0], s11 = sim[(r0 + 1) * 20 + c0 + 1];
      simr[t] = (1.0f - fy) * ((1.0f - fx) * s00 + fx * s01) + fy * ((1.0f - fx) * s10 + fx * s11);
    }
    __syncthreads();
    const float* cw = CW[li];
    const float* cb = CB[li];
    for (int idx = t; idx < 800; idx += 256) {
      int cch = idx / 100, rem = idx % 100, y = rem / 10, x = rem % 10;
      float a = cb[cch];
#pragma unroll
      for (int ky = 0; ky < 3; ++ky) {
#pragma unroll
        for (int kx = 0; kx < 3; ++kx) {
          int iy = y + ky - 1, ix = x + kx - 1;
          if (iy >= 0 && iy < 10 && ix >= 0 && ix < 10)
            a += cw[cch * 9 + ky * 3 + kx] * simr[iy * 10 + ix];
        }
      }
      feat[li * 800 + idx] = fmaxf(a, 0.0f);
    }
    __syncthreads();
  }

  // MLP0: 2400 -> 32, 8 partial sums per output
  {
    int f = t & 31, part = t >> 5;
    float a = 0.0f;
    int k0 = part * 300;
    for (int k = k0; k < k0 + 300; ++k) a += feat[k] * mw0[k * 32 + f];
    red[t] = a;
    __syncthreads();
    if (t < 32) {
      float s = mb0[t];
#pragma unroll
      for (int p = 0; p < 8; ++p) s += red[p * 32 + t];
      mbuf[t] = fmaxf(s, 0.0f);
    }
    __syncthreads();
  }
  if (t < 16) {
    float s = mb1[t];
    for (int k = 0; k < 32; ++k) s += mbuf[k] * mw1[k * 16 + t];
    mbuf[32 + t] = fmaxf(s, 0.0f);
  }
  __syncthreads();
  if (t < 8) {
    float s = mb2[t];
    for (int k = 0; k < 16; ++k) s += mbuf[32 + k] * mw2[k * 8 + t];
    mbuf[48 + t] = fmaxf(s, 0.0f);
  }
  __syncthreads();
  if (t < 4) {
    float s = mb3[t];
    for (int k = 0; k < 8; ++k) s += mbuf[48 + k] * mw3[k * 4 + t];
    mbuf[56 + t] = fmaxf(s, 0.0f);
  }
  __syncthreads();
  if (t == 0) {
    float s = mb4[0];
    for (int k = 0; k < 4; ++k) s += mbuf[56 + k] * mw4[k];
    s = fmaxf(s, 0.0f);
    float z = s * sw[0] + sb[0];
    out[b] = 1.0f / (1.0f + expf(-z));
  }
}

extern "C" void kernel_launch(void* const* d_in, const int* in_sizes, int n_in,
                              void* d_out, int out_size, void* d_ws, size_t ws_size,
                              hipStream_t stream) {
  (void)in_sizes; (void)n_in; (void)out_size; (void)ws_size;
  const float* x_i = (const float*)d_in[0];
  const float* x_j = (const float*)d_in[1];
  const float* gw0 = (const float*)d_in[2];
  const float* gb0 = (const float*)d_in[3];
  const float* gw1 = (const float*)d_in[4];
  const float* gb1 = (const float*)d_in[5];
  const float* gw2 = (const float*)d_in[6];
  const float* gb2 = (const float*)d_in[7];
  const float* cw0 = (const float*)d_in[8];
  const float* cb0 = (const float*)d_in[9];
  const float* cw1 = (const float*)d_in[10];
  const float* cb1 = (const float*)d_in[11];
  const float* cw2 = (const float*)d_in[12];
  const float* cb2 = (const float*)d_in[13];
  const float* mw0 = (const float*)d_in[14];
  const float* mb0 = (const float*)d_in[15];
  const float* mw1 = (const float*)d_in[16];
  const float* mb1 = (const float*)d_in[17];
  const float* mw2 = (const float*)d_in[18];
  const float* mb2 = (const float*)d_in[19];
  const float* mw3 = (const float*)d_in[20];
  const float* mb3 = (const float*)d_in[21];
  const float* mw4 = (const float*)d_in[22];
  const float* mb4 = (const float*)d_in[23];
  const float* scw = (const float*)d_in[24];
  const float* scb = (const float*)d_in[25];
  const int* ei = (const int*)d_in[26];
  const int* ej = (const int*)d_in[27];
  float* out = (float*)d_out;

  char* p = (char*)d_ws;
  auto take = [&](size_t bytes) {
    char* r = p;
    p += (bytes + 255) & ~(size_t)255;
    return r;
  };
  float* hs0 = (float*)take((size_t)2 * BB * 20 * 64 * 4);
  float* hs1 = (float*)take((size_t)2 * BB * 20 * 32 * 4);
  float* hs2 = (float*)take((size_t)2 * BB * 20 * 16 * 4);

  k_all<<<2 * BB, 1024, 0, stream>>>(x_i, x_j, gw0, gb0, gw1, gb1, gw2, gb2,
                                     ei, ej, hs0, hs1, hs2);
  k_head<<<BB, 256, 0, stream>>>(hs0, hs1, hs2, cw0, cb0, cw1, cb1, cw2, cb2,
                                 mw0, mb0, mw1, mb1, mw2, mb2, mw3, mb3, mw4, mb4,
                                 scw, scb, out);
}

// Round 16
// 132.565 us; speedup vs baseline: 4.6594x; 4.6594x over previous
//
#include <hip/hip_runtime.h>

typedef float fvec4 __attribute__((ext_vector_type(4)));

#define NN 65536      // total nodes per side (B*NPG)
#define EE 1048576    // edges per side (B*NPG*DEG)
#define BB 128
#define NPG 512
#define EPG 8192      // edges per graph (NPG*DEG)

// ---------------- one block per (side, graph): CSR build + degree-sort + 3 GCN layers ----------------
// Msg layout: node's row = 8 fvec4 quads at (node<<3); quad q lives at index key^q where
// key = (node<<3)|(node&7)  (XOR swizzle: bijective per row, uniform bank groups for
// random nodes). sids[] holds the pre-swizzled u16 keys, CSR-bucketed by dst.
// L0 gathers BOTH 32-feature halves (bufA/bufB) in one edge loop.
__global__ __launch_bounds__(512)
void k_all(const float* __restrict__ x_i, const float* __restrict__ x_j,
           const float* __restrict__ gw0, const float* __restrict__ gb0,
           const float* __restrict__ gw1, const float* __restrict__ gb1,
           const float* __restrict__ gw2, const float* __restrict__ gb2,
           const int* __restrict__ ei, const int* __restrict__ ej,
           float* __restrict__ hs0, float* __restrict__ hs1, float* __restrict__ hs2) {
  __shared__ fvec4 bufA[NPG * 8];         // 64 KB (aliases dsts staging in prep)
  __shared__ fvec4 bufB[NPG * 8];         // 64 KB
  __shared__ unsigned short sids[EPG];    // 16 KB: pre-swizzled keys
  __shared__ int cnt[NPG];
  __shared__ int posb[NPG];
  __shared__ int nodeOf[NPG];
  __shared__ int bins[64];
  __shared__ int binpos[64];
  __shared__ int wsum[8];
  unsigned short* const dsts = reinterpret_cast<unsigned short*>(bufA);  // prep-only

  const int side = blockIdx.x >> 7;
  const int g = blockIdx.x & 127;
  const float* __restrict__ x = side ? x_j : x_i;
  const int* __restrict__ eidx = side ? ej : ei;
  const int v = threadIdx.x;
  const int base = g * NPG;
  const int ebase = g * EPG;

  // ---- degree count ----
  cnt[v] = 0;
  if (v < 64) bins[v] = 0;
  __syncthreads();
  for (int k = v; k < EPG; k += 512) {
    int d = eidx[EE + ebase + k] - base;
    dsts[k] = (unsigned short)d;
    atomicAdd(&cnt[d], 1);
  }
  __syncthreads();

  // ---- scan over 512 counts + degree histogram ----
  const int count = cnt[v];
  const int deg = count > 63 ? 63 : count;
  atomicAdd(&bins[deg], 1);
  int xa = count;
  const int lane = v & 63;
#pragma unroll
  for (int d = 1; d < 64; d <<= 1) {
    int y = __shfl_up(xa, d, 64);
    if (lane >= d) xa += y;
  }
  const int wid = v >> 6;
  if (lane == 63) wsum[wid] = xa;
  __syncthreads();
  if (v < 64) {
    if (v == 0) {
      int a = 0;
#pragma unroll
      for (int i = 0; i < 8; ++i) { int tv = wsum[i]; wsum[i] = a; a += tv; }
    }
    int c = bins[v];
    int xb = c;
#pragma unroll
    for (int d = 1; d < 64; d <<= 1) {
      int y = __shfl_up(xb, d, 64);
      if (v >= d) xb += y;
    }
    binpos[v] = xb - c;
  }
  __syncthreads();
  const int start_v = xa - count + wsum[wid];
  posb[v] = start_v;
  {
    int rank = atomicAdd(&binpos[deg], 1);
    nodeOf[rank] = v;
  }
  __syncthreads();

  // ---- CSR fill with pre-swizzled u16 keys ----
  for (int k = v; k < EPG; k += 512) {
    int lv = eidx[ebase + k] - base;
    int p = atomicAdd(&posb[dsts[k]], 1);
    sids[p] = (unsigned short)((lv << 3) | (lv & 7));
  }
  __syncthreads();

  // ---- this thread owns node = nodeOf[v] (wave-uniform degrees) ----
  const int node = nodeOf[v];
  const int ncount = cnt[node];
  const int nstart = posb[node] - ncount;
  const float inv_v = rsqrtf((float)ncount + 1.0f);
  const int myKey = (node << 3) | (node & 7);

  constexpr int srows[20] = {25, 26, 76, 77, 127, 128, 178, 179, 229, 230,
                             281, 282, 332, 333, 383, 384, 434, 435, 485, 486};
  int slot = -1;
#pragma unroll
  for (int i = 0; i < 20; ++i)
    if (node == srows[i]) slot = i;
  const int hb = (side * BB + g) * 20;

  // ---- layer 0: full xW0 row in one streaming pass over x ----
  fvec4 a0[16];
#pragma unroll
  for (int q = 0; q < 16; ++q) a0[q] = fvec4{0.f, 0.f, 0.f, 0.f};
  {
    const fvec4* xv = reinterpret_cast<const fvec4*>(x + (size_t)(base + node) * 64);
#pragma unroll 1
    for (int k16 = 0; k16 < 4; ++k16) {
      fvec4 xq[4];
#pragma unroll
      for (int u = 0; u < 4; ++u) xq[u] = xv[4 * k16 + u];
#pragma unroll
      for (int u = 0; u < 4; ++u) {
#pragma unroll
        for (int j = 0; j < 4; ++j) {
          const float xk = xq[u][j];
          const fvec4* wr = reinterpret_cast<const fvec4*>(gw0 + (size_t)(16 * k16 + 4 * u + j) * 64);
#pragma unroll
          for (int q = 0; q < 16; ++q) a0[q] += xk * wr[q];
        }
      }
    }
  }

  // ---- L0 publish both halves (f32), self-init s, a0 dies ----
  fvec4 sA[8], sB[8];
#pragma unroll
  for (int q = 0; q < 8; ++q) {
    fvec4 mA = a0[q] * inv_v;
    fvec4 mB = a0[8 + q] * inv_v;
    bufA[myKey ^ q] = mA;
    bufB[myKey ^ q] = mB;
    sA[q] = mA;
    sB[q] = mB;
  }
  __syncthreads();

  // ---- L0 merged gather: both halves per edge (16 b128 reads in flight) ----
  {
    const int end = nstart + ncount;
    for (int e = nstart; e < end; ++e) {
      const int K = sids[e];
#pragma unroll
      for (int q = 0; q < 8; ++q) {
        const int idx = K ^ q;
        sA[q] += bufA[idx];
        sB[q] += bufB[idx];
      }
    }
  }

  // ---- L0 epilogue: h0 = relu(s*inv + b0); fold y1 = h0*W1; hs0 ----
  fvec4 y1[8];
#pragma unroll
  for (int p = 0; p < 8; ++p) y1[p] = fvec4{0.f, 0.f, 0.f, 0.f};
  {
    const fvec4* gb0v = reinterpret_cast<const fvec4*>(gb0);
    fvec4* hp = reinterpret_cast<fvec4*>(hs0 + ((size_t)hb + slot) * 64);
#pragma unroll
    for (int q = 0; q < 16; ++q) {
      fvec4 s = (q < 8) ? sA[q] : sB[q - 8];
      fvec4 o = s * inv_v + gb0v[q];
#pragma unroll
      for (int j = 0; j < 4; ++j) o[j] = fmaxf(o[j], 0.f);
      if (slot >= 0) hp[q] = o;
#pragma unroll
      for (int j = 0; j < 4; ++j) {
        const float hf = o[j];
        const fvec4* wr = reinterpret_cast<const fvec4*>(gw1 + (size_t)(q * 4 + j) * 32);
#pragma unroll
        for (int p = 0; p < 8; ++p) y1[p] += hf * wr[p];
      }
    }
  }
  __syncthreads();  // all L0 gather reads complete

  // ---- L1: publish y1 into bufA, gather, fold y2 ----
  fvec4 s1[8];
#pragma unroll
  for (int q = 0; q < 8; ++q) {
    fvec4 mv = y1[q] * inv_v;
    bufA[myKey ^ q] = mv;
    s1[q] = mv;
  }
  __syncthreads();
  {
    const int end = nstart + ncount;
    for (int e = nstart; e < end; ++e) {
      const int K = sids[e];
#pragma unroll
      for (int q = 0; q < 8; ++q) s1[q] += bufA[K ^ q];
    }
  }
  fvec4 y2[4];
#pragma unroll
  for (int p = 0; p < 4; ++p) y2[p] = fvec4{0.f, 0.f, 0.f, 0.f};
  {
    const fvec4* gb1v = reinterpret_cast<const fvec4*>(gb1);
    fvec4* hp = reinterpret_cast<fvec4*>(hs1 + ((size_t)hb + slot) * 32);
#pragma unroll
    for (int q = 0; q < 8; ++q) {
      fvec4 o = s1[q] * inv_v + gb1v[q];
#pragma unroll
      for (int j = 0; j < 4; ++j) o[j] = fmaxf(o[j], 0.f);
      if (slot >= 0) hp[q] = o;
#pragma unroll
      for (int j = 0; j < 4; ++j) {
        const float hf = o[j];
        const fvec4* wr = reinterpret_cast<const fvec4*>(gw2 + (size_t)(q * 4 + j) * 16);
#pragma unroll
        for (int p = 0; p < 4; ++p) y2[p] += hf * wr[p];
      }
    }
  }

  // ---- L2: publish y2 into bufB (last read of bufB was L0 gather — safe) ----
  fvec4 s2[4];
#pragma unroll
  for (int q = 0; q < 4; ++q) {
    fvec4 mv = y2[q] * inv_v;
    bufB[myKey ^ q] = mv;
    s2[q] = mv;
  }
  __syncthreads();
  if (slot >= 0) {
    const int end = nstart + ncount;
    for (int e = nstart; e < end; ++e) {
      const int K = sids[e];
#pragma unroll
      for (int q = 0; q < 4; ++q) s2[q] += bufB[K ^ q];
    }
    const fvec4* gb2v = reinterpret_cast<const fvec4*>(gb2);
    fvec4* hp = reinterpret_cast<fvec4*>(hs2 + ((size_t)hb + slot) * 16);
#pragma unroll
    for (int q = 0; q < 4; ++q) hp[q] = s2[q] * inv_v + gb2v[q];
  }
}

// ---------------- head: sampled sim -> bilinear 10x10 -> conv3x3(1->8) -> MLP -> sigmoid ----------------
__global__ __launch_bounds__(256) void k_head(const float* __restrict__ hs0, const float* __restrict__ hs1,
                                              const float* __restrict__ hs2,
                                              const float* __restrict__ cw0, const float* __restrict__ cb0,
                                              const float* __restrict__ cw1, const float* __restrict__ cb1,
                                              const float* __restrict__ cw2, const float* __restrict__ cb2,
                                              const float* __restrict__ mw0, const float* __restrict__ mb0,
                                              const float* __restrict__ mw1, const float* __restrict__ mb1,
                                              const float* __restrict__ mw2, const float* __restrict__ mb2,
                                              const float* __restrict__ mw3, const float* __restrict__ mb3,
                                              const float* __restrict__ mw4, const float* __restrict__ mb4,
                                              const float* __restrict__ sw, const float* __restrict__ sb,
                                              float* __restrict__ out) {
  __shared__ float hi[2240];  // 20*64 + 20*32 + 20*16
  __shared__ float hj[2240];
  __shared__ float sim[400];
  __shared__ float simr[100];
  __shared__ float feat[2400];
  __shared__ float red[256];
  __shared__ float mbuf[60];
  const int b = blockIdx.x, t = threadIdx.x;

  for (int k = t; k < 1280; k += 256) {
    hi[k] = hs0[(size_t)(0 * BB + b) * 1280 + k];
    hj[k] = hs0[(size_t)(1 * BB + b) * 1280 + k];
  }
  for (int k = t; k < 640; k += 256) {
    hi[1280 + k] = hs1[(size_t)(0 * BB + b) * 640 + k];
    hj[1280 + k] = hs1[(size_t)(1 * BB + b) * 640 + k];
  }
  for (int k = t; k < 320; k += 256) {
    hi[1920 + k] = hs2[(size_t)(0 * BB + b) * 320 + k];
    hj[1920 + k] = hs2[(size_t)(1 * BB + b) * 320 + k];
  }
  __syncthreads();

  const int Fs[3] = {64, 32, 16};
  const int HOFF[3] = {0, 1280, 1920};
  const float* CW[3] = {cw0, cw1, cw2};
  const float* CB[3] = {cb0, cb1, cb2};

  for (int li = 0; li < 3; ++li) {
    const int F = Fs[li];
    const float* Hi = hi + HOFF[li];
    const float* Hj = hj + HOFF[li];
    for (int p = t; p < 400; p += 256) {
      int r = p / 20, cq = p % 20;
      float a = 0.0f;
      for (int d = 0; d < F; ++d) a += Hi[r * F + d] * Hj[cq * F + d];
      sim[p] = a;
    }
    __syncthreads();
    if (t < 100) {
      int oy = t / 10, ox = t % 10;
      float cy = (oy + 0.5f) * (512.0f / 10.0f) - 0.5f;
      float cx = (ox + 0.5f) * (512.0f / 10.0f) - 0.5f;
      float fy = cy - floorf(cy);
      float fx = cx - floorf(cx);
      int r0 = 2 * oy, c0 = 2 * ox;
      float s00 = sim[r0 * 20 + c0], s01 = sim[r0 * 20 + c0 + 1];
      float s10 = sim[(r0 + 1) * 20 + c0], s11 = sim[(r0 + 1) * 20 + c0 + 1];
      simr[t] = (1.0f - fy) * ((1.0f - fx) * s00 + fx * s01) + fy * ((1.0f - fx) * s10 + fx * s11);
    }
    __syncthreads();
    const float* cw = CW[li];
    const float* cb = CB[li];
    for (int idx = t; idx < 800; idx += 256) {
      int cch = idx / 100, rem = idx % 100, y = rem / 10, x = rem % 10;
      float a = cb[cch];
#pragma unroll
      for (int ky = 0; ky < 3; ++ky) {
#pragma unroll
        for (int kx = 0; kx < 3; ++kx) {
          int iy = y + ky - 1, ix = x + kx - 1;
          if (iy >= 0 && iy < 10 && ix >= 0 && ix < 10)
            a += cw[cch * 9 + ky * 3 + kx] * simr[iy * 10 + ix];
        }
      }
      feat[li * 800 + idx] = fmaxf(a, 0.0f);
    }
    __syncthreads();
  }

  // MLP0: 2400 -> 32, 8 partial sums per output
  {
    int f = t & 31, part = t >> 5;
    float a = 0.0f;
    int k0 = part * 300;
    for (int k = k0; k < k0 + 300; ++k) a += feat[k] * mw0[k * 32 + f];
    red[t] = a;
    __syncthreads();
    if (t < 32) {
      float s = mb0[t];
#pragma unroll
      for (int p = 0; p < 8; ++p) s += red[p * 32 + t];
      mbuf[t] = fmaxf(s, 0.0f);
    }
    __syncthreads();
  }
  if (t < 16) {
    float s = mb1[t];
    for (int k = 0; k < 32; ++k) s += mbuf[k] * mw1[k * 16 + t];
    mbuf[32 + t] = fmaxf(s, 0.0f);
  }
  __syncthreads();
  if (t < 8) {
    float s = mb2[t];
    for (int k = 0; k < 16; ++k) s += mbuf[32 + k] * mw2[k * 8 + t];
    mbuf[48 + t] = fmaxf(s, 0.0f);
  }
  __syncthreads();
  if (t < 4) {
    float s = mb3[t];
    for (int k = 0; k < 8; ++k) s += mbuf[48 + k] * mw3[k * 4 + t];
    mbuf[56 + t] = fmaxf(s, 0.0f);
  }
  __syncthreads();
  if (t == 0) {
    float s = mb4[0];
    for (int k = 0; k < 4; ++k) s += mbuf[56 + k] * mw4[k];
    s = fmaxf(s, 0.0f);
    float z = s * sw[0] + sb[0];
    out[b] = 1.0f / (1.0f + expf(-z));
  }
}

extern "C" void kernel_launch(void* const* d_in, const int* in_sizes, int n_in,
                              void* d_out, int out_size, void* d_ws, size_t ws_size,
                              hipStream_t stream) {
  (void)in_sizes; (void)n_in; (void)out_size; (void)ws_size;
  const float* x_i = (const float*)d_in[0];
  const float* x_j = (const float*)d_in[1];
  const float* gw0 = (const float*)d_in[2];
  const float* gb0 = (const float*)d_in[3];
  const float* gw1 = (const float*)d_in[4];
  const float* gb1 = (const float*)d_in[5];
  const float* gw2 = (const float*)d_in[6];
  const float* gb2 = (const float*)d_in[7];
  const float* cw0 = (const float*)d_in[8];
  const float* cb0 = (const float*)d_in[9];
  const float* cw1 = (const float*)d_in[10];
  const float* cb1 = (const float*)d_in[11];
  const float* cw2 = (const float*)d_in[12];
  const float* cb2 = (const float*)d_in[13];
  const float* mw0 = (const float*)d_in[14];
  const float* mb0 = (const float*)d_in[15];
  const float* mw1 = (const float*)d_in[16];
  const float* mb1 = (const float*)d_in[17];
  const float* mw2 = (const float*)d_in[18];
  const float* mb2 = (const float*)d_in[19];
  const float* mw3 = (const float*)d_in[20];
  const float* mb3 = (const float*)d_in[21];
  const float* mw4 = (const float*)d_in[22];
  const float* mb4 = (const float*)d_in[23];
  const float* scw = (const float*)d_in[24];
  const float* scb = (const float*)d_in[25];
  const int* ei = (const int*)d_in[26];
  const int* ej = (const int*)d_in[27];
  float* out = (float*)d_out;

  char* p = (char*)d_ws;
  auto take = [&](size_t bytes) {
    char* r = p;
    p += (bytes + 255) & ~(size_t)255;
    return r;
  };
  float* hs0 = (float*)take((size_t)2 * BB * 20 * 64 * 4);
  float* hs1 = (float*)take((size_t)2 * BB * 20 * 32 * 4);
  float* hs2 = (float*)take((size_t)2 * BB * 20 * 16 * 4);

  k_all<<<2 * BB, 512, 0, stream>>>(x_i, x_j, gw0, gb0, gw1, gb1, gw2, gb2,
                                    ei, ej, hs0, hs1, hs2);
  k_head<<<BB, 256, 0, stream>>>(hs0, hs1, hs2, cw0, cb0, cw1, cb1, cw2, cb2,
                                 mw0, mb0, mw1, mb1, mw2, mb2, mw3, mb3, mw4, mb4,
                                 scw, scb, out);
}

// Round 18
// 131.656 us; speedup vs baseline: 4.6916x; 1.0069x over previous
//
#include <hip/hip_runtime.h>
#include <hip/hip_fp16.h>

typedef float fvec4 __attribute__((ext_vector_type(4)));
typedef int ivec4 __attribute__((ext_vector_type(4)));

#define NN 65536      // total nodes per side (B*NPG)
#define EE 1048576    // edges per side (B*NPG*DEG)
#define BB 128
#define NPG 512
#define EPG 8192      // edges per graph (NPG*DEG)

__device__ __forceinline__ int pkrtz(float a, float b) {
  union { __half2 h; int i; } u; u.h = __floats2half2_rn(a, b); return u.i;
}
__device__ __forceinline__ float2 up2(int v) {
  union { int i; __half2 h; } u; u.i = v; return __half22float2(u.h);
}

// accumulate one 16B quad (8 f16) into two fvec4 f32 partial sums
#define ACCQ(SA, SB, w) { float2 f_; \
  f_ = up2((w)[0]); (SA)[0] += f_.x; (SA)[1] += f_.y; \
  f_ = up2((w)[1]); (SA)[2] += f_.x; (SA)[3] += f_.y; \
  f_ = up2((w)[2]); (SB)[0] += f_.x; (SB)[1] += f_.y; \
  f_ = up2((w)[3]); (SB)[2] += f_.x; (SB)[3] += f_.y; }

// ---------------- one block per (side, graph): CSR build + degree-sort + 3 GCN layers ----------------
// f16 messages, f32 accumulation. Row r = 4 quads (64B); quad q at index key^q with
// key = (r<<2) | ((r>>1)&3)  -> for fixed q, random r spreads over all 8 bank groups.
// sids[] holds pre-swizzled u16 keys, CSR-bucketed by dst. Unmerged 32-feature passes
// keep gather-live accumulators at 8 fvec4 (no spill; R14/R16 lesson).
__global__ __launch_bounds__(512)
void k_all(const float* __restrict__ x_i, const float* __restrict__ x_j,
           const float* __restrict__ gw0, const float* __restrict__ gb0,
           const float* __restrict__ gw1, const float* __restrict__ gb1,
           const float* __restrict__ gw2, const float* __restrict__ gb2,
           const int* __restrict__ ei, const int* __restrict__ ej,
           float* __restrict__ hs0, float* __restrict__ hs1, float* __restrict__ hs2) {
  __shared__ ivec4 bufA[NPG * 4];         // 32 KB (aliases dsts staging in prep)
  __shared__ ivec4 bufB[NPG * 4];         // 32 KB
  __shared__ unsigned short sids[EPG];    // 16 KB: pre-swizzled keys
  __shared__ int cnt[NPG];
  __shared__ int posb[NPG];
  __shared__ int nodeOf[NPG];
  __shared__ int bins[64];
  __shared__ int binpos[64];
  __shared__ int wsum[8];
  unsigned short* const dsts = reinterpret_cast<unsigned short*>(bufA);  // prep-only

  const int side = blockIdx.x >> 7;
  const int g = blockIdx.x & 127;
  const float* __restrict__ x = side ? x_j : x_i;
  const int* __restrict__ eidx = side ? ej : ei;
  const int v = threadIdx.x;
  const int base = g * NPG;
  const int ebase = g * EPG;

  // ---- degree count ----
  cnt[v] = 0;
  if (v < 64) bins[v] = 0;
  __syncthreads();
  for (int k = v; k < EPG; k += 512) {
    int d = eidx[EE + ebase + k] - base;
    dsts[k] = (unsigned short)d;
    atomicAdd(&cnt[d], 1);
  }
  __syncthreads();

  // ---- scan over 512 counts + degree histogram ----
  const int count = cnt[v];
  const int deg = count > 63 ? 63 : count;
  atomicAdd(&bins[deg], 1);
  int xa = count;
  const int lane = v & 63;
#pragma unroll
  for (int d = 1; d < 64; d <<= 1) {
    int y = __shfl_up(xa, d, 64);
    if (lane >= d) xa += y;
  }
  const int wid = v >> 6;
  if (lane == 63) wsum[wid] = xa;
  __syncthreads();
  if (v < 64) {
    if (v == 0) {
      int a = 0;
#pragma unroll
      for (int i = 0; i < 8; ++i) { int tv = wsum[i]; wsum[i] = a; a += tv; }
    }
    int c = bins[v];
    int xb = c;
#pragma unroll
    for (int d = 1; d < 64; d <<= 1) {
      int y = __shfl_up(xb, d, 64);
      if (v >= d) xb += y;
    }
    binpos[v] = xb - c;
  }
  __syncthreads();
  const int start_v = xa - count + wsum[wid];
  posb[v] = start_v;
  {
    int rank = atomicAdd(&binpos[deg], 1);
    nodeOf[rank] = v;
  }
  __syncthreads();

  // ---- CSR fill with pre-swizzled u16 keys ----
  for (int k = v; k < EPG; k += 512) {
    int lv = eidx[ebase + k] - base;
    int p = atomicAdd(&posb[dsts[k]], 1);
    sids[p] = (unsigned short)((lv << 2) | ((lv >> 1) & 3));
  }
  __syncthreads();

  // ---- this thread owns node = nodeOf[v] (wave-uniform degrees) ----
  const int node = nodeOf[v];
  const int ncount = cnt[node];
  const int nstart = posb[node] - ncount;
  const float inv_v = rsqrtf((float)ncount + 1.0f);
  const int myKey = (node << 2) | ((node >> 1) & 3);

  constexpr int srows[20] = {25, 26, 76, 77, 127, 128, 178, 179, 229, 230,
                             281, 282, 332, 333, 383, 384, 434, 435, 485, 486};
  int slot = -1;
#pragma unroll
  for (int i = 0; i < 20; ++i)
    if (node == srows[i]) slot = i;
  const int hb = (side * BB + g) * 20;

  // ---- layer 0: full xW0 row in one streaming pass over x ----
  fvec4 a0[16];
#pragma unroll
  for (int q = 0; q < 16; ++q) a0[q] = fvec4{0.f, 0.f, 0.f, 0.f};
  {
    const fvec4* xv = reinterpret_cast<const fvec4*>(x + (size_t)(base + node) * 64);
#pragma unroll 1
    for (int k16 = 0; k16 < 4; ++k16) {
      fvec4 xq[4];
#pragma unroll
      for (int u = 0; u < 4; ++u) xq[u] = xv[4 * k16 + u];
#pragma unroll
      for (int u = 0; u < 4; ++u) {
#pragma unroll
        for (int j = 0; j < 4; ++j) {
          const float xk = xq[u][j];
          const fvec4* wr = reinterpret_cast<const fvec4*>(gw0 + (size_t)(16 * k16 + 4 * u + j) * 64);
#pragma unroll
          for (int q = 0; q < 16; ++q) a0[q] += xk * wr[q];
        }
      }
    }
  }

  // ---- L0a: scale + publish feats[0:32) to bufA; s = self msg (f32 exact) ----
  fvec4 s[8];
#pragma unroll
  for (int q = 0; q < 8; ++q) s[q] = a0[q] * inv_v;
#pragma unroll
  for (int q_ = 0; q_ < 4; ++q_) {
    ivec4 w_;
    w_[0] = pkrtz(s[2 * q_][0], s[2 * q_][1]);
    w_[1] = pkrtz(s[2 * q_][2], s[2 * q_][3]);
    w_[2] = pkrtz(s[2 * q_ + 1][0], s[2 * q_ + 1][1]);
    w_[3] = pkrtz(s[2 * q_ + 1][2], s[2 * q_ + 1][3]);
    bufA[myKey ^ q_] = w_;
  }
  __syncthreads();

  // ---- L0a gather ----
  {
    const int end = nstart + ncount;
    for (int e = nstart; e < end; ++e) {
      const int K = sids[e];
      const ivec4 w0 = bufA[K], w1 = bufA[K ^ 1], w2 = bufA[K ^ 2], w3 = bufA[K ^ 3];
      ACCQ(s[0], s[1], w0) ACCQ(s[2], s[3], w1) ACCQ(s[4], s[5], w2) ACCQ(s[6], s[7], w3)
    }
  }

  // ---- L0b: scale + publish feats[32:64) to bufB (disjoint buffer, no sync needed) ----
  fvec4 sB[8];
#pragma unroll
  for (int q = 0; q < 8; ++q) sB[q] = a0[8 + q] * inv_v;
#pragma unroll
  for (int q_ = 0; q_ < 4; ++q_) {
    ivec4 w_;
    w_[0] = pkrtz(sB[2 * q_][0], sB[2 * q_][1]);
    w_[1] = pkrtz(sB[2 * q_][2], sB[2 * q_][3]);
    w_[2] = pkrtz(sB[2 * q_ + 1][0], sB[2 * q_ + 1][1]);
    w_[3] = pkrtz(sB[2 * q_ + 1][2], sB[2 * q_ + 1][3]);
    bufB[myKey ^ q_] = w_;
  }

  // ---- L0a epilogue: h0a = relu(s*inv + b); fold y1 += h0a * W1[0:32,:] ----
  fvec4 y1[8];
#pragma unroll
  for (int p = 0; p < 8; ++p) y1[p] = fvec4{0.f, 0.f, 0.f, 0.f};
  {
    const fvec4* gb0v = reinterpret_cast<const fvec4*>(gb0);
    fvec4* hp = reinterpret_cast<fvec4*>(hs0 + ((size_t)hb + slot) * 64);
#pragma unroll
    for (int q = 0; q < 8; ++q) {
      fvec4 o = s[q] * inv_v + gb0v[q];
#pragma unroll
      for (int j = 0; j < 4; ++j) o[j] = fmaxf(o[j], 0.f);
      if (slot >= 0) hp[q] = o;
#pragma unroll
      for (int j = 0; j < 4; ++j) {
        const float hf = o[j];
        const fvec4* wr = reinterpret_cast<const fvec4*>(gw1 + (size_t)(q * 4 + j) * 32);
#pragma unroll
        for (int p = 0; p < 8; ++p) y1[p] += hf * wr[p];
      }
    }
  }
  __syncthreads();  // pubB visible; all L0a gathers done (bufA free)

  // ---- L0b gather ----
  {
    const int end = nstart + ncount;
    for (int e = nstart; e < end; ++e) {
      const int K = sids[e];
      const ivec4 w0 = bufB[K], w1 = bufB[K ^ 1], w2 = bufB[K ^ 2], w3 = bufB[K ^ 3];
      ACCQ(sB[0], sB[1], w0) ACCQ(sB[2], sB[3], w1) ACCQ(sB[4], sB[5], w2) ACCQ(sB[6], sB[7], w3)
    }
  }
  // ---- L0b epilogue: fold y1 += h0b * W1[32:64,:] ----
  {
    const fvec4* gb0v = reinterpret_cast<const fvec4*>(gb0);
    fvec4* hp = reinterpret_cast<fvec4*>(hs0 + ((size_t)hb + slot) * 64);
#pragma unroll
    for (int q = 0; q < 8; ++q) {
      fvec4 o = sB[q] * inv_v + gb0v[8 + q];
#pragma unroll
      for (int j = 0; j < 4; ++j) o[j] = fmaxf(o[j], 0.f);
      if (slot >= 0) hp[8 + q] = o;
#pragma unroll
      for (int j = 0; j < 4; ++j) {
        const float hf = o[j];
        const fvec4* wr = reinterpret_cast<const fvec4*>(gw1 + (size_t)((8 + q) * 4 + j) * 32);
#pragma unroll
        for (int p = 0; p < 8; ++p) y1[p] += hf * wr[p];
      }
    }
  }

  // ---- L1: scale + publish y1 into bufA (free since barrier above) ----
  fvec4 s1[8];
#pragma unroll
  for (int q = 0; q < 8; ++q) s1[q] = y1[q] * inv_v;
#pragma unroll
  for (int q_ = 0; q_ < 4; ++q_) {
    ivec4 w_;
    w_[0] = pkrtz(s1[2 * q_][0], s1[2 * q_][1]);
    w_[1] = pkrtz(s1[2 * q_][2], s1[2 * q_][3]);
    w_[2] = pkrtz(s1[2 * q_ + 1][0], s1[2 * q_ + 1][1]);
    w_[3] = pkrtz(s1[2 * q_ + 1][2], s1[2 * q_ + 1][3]);
    bufA[myKey ^ q_] = w_;
  }
  __syncthreads();  // pub L1 visible; all L0b gathers done (bufB free)

  // ---- L1 gather ----
  {
    const int end = nstart + ncount;
    for (int e = nstart; e < end; ++e) {
      const int K = sids[e];
      const ivec4 w0 = bufA[K], w1 = bufA[K ^ 1], w2 = bufA[K ^ 2], w3 = bufA[K ^ 3];
      ACCQ(s1[0], s1[1], w0) ACCQ(s1[2], s1[3], w1) ACCQ(s1[4], s1[5], w2) ACCQ(s1[6], s1[7], w3)
    }
  }
  // ---- L1 epilogue: h1 = relu(...); fold y2 = h1*W2; hs1 ----
  fvec4 y2[4];
#pragma unroll
  for (int p = 0; p < 4; ++p) y2[p] = fvec4{0.f, 0.f, 0.f, 0.f};
  {
    const fvec4* gb1v = reinterpret_cast<const fvec4*>(gb1);
    fvec4* hp = reinterpret_cast<fvec4*>(hs1 + ((size_t)hb + slot) * 32);
#pragma unroll
    for (int q = 0; q < 8; ++q) {
      fvec4 o = s1[q] * inv_v + gb1v[q];
#pragma unroll
      for (int j = 0; j < 4; ++j) o[j] = fmaxf(o[j], 0.f);
      if (slot >= 0) hp[q] = o;
#pragma unroll
      for (int j = 0; j < 4; ++j) {
        const float hf = o[j];
        const fvec4* wr = reinterpret_cast<const fvec4*>(gw2 + (size_t)(q * 4 + j) * 16);
#pragma unroll
        for (int p = 0; p < 4; ++p) y2[p] += hf * wr[p];
      }
    }
  }

  // ---- L2: scale + publish y2 (16 feats = 2 quads) into bufB ----
  fvec4 s2[4];
#pragma unroll
  for (int q = 0; q < 4; ++q) s2[q] = y2[q] * inv_v;
  {
    ivec4 w0, w1;
    w0[0] = pkrtz(s2[0][0], s2[0][1]); w0[1] = pkrtz(s2[0][2], s2[0][3]);
    w0[2] = pkrtz(s2[1][0], s2[1][1]); w0[3] = pkrtz(s2[1][2], s2[1][3]);
    w1[0] = pkrtz(s2[2][0], s2[2][1]); w1[1] = pkrtz(s2[2][2], s2[2][3]);
    w1[2] = pkrtz(s2[3][0], s2[3][1]); w1[3] = pkrtz(s2[3][2], s2[3][3]);
    bufB[myKey] = w0;
    bufB[myKey ^ 1] = w1;
  }
  __syncthreads();  // pub L2 visible; all L1 gathers done

  // ---- L2 gather: only sampled rows ----
  if (slot >= 0) {
    const int end = nstart + ncount;
    for (int e = nstart; e < end; ++e) {
      const int K = sids[e];
      const ivec4 w0 = bufB[K], w1 = bufB[K ^ 1];
      ACCQ(s2[0], s2[1], w0) ACCQ(s2[2], s2[3], w1)
    }
    const fvec4* gb2v = reinterpret_cast<const fvec4*>(gb2);
    fvec4* hp = reinterpret_cast<fvec4*>(hs2 + ((size_t)hb + slot) * 16);
#pragma unroll
    for (int q = 0; q < 4; ++q) hp[q] = s2[q] * inv_v + gb2v[q];
  }
}

// ---------------- head: sampled sim -> bilinear 10x10 -> conv3x3(1->8) -> MLP -> sigmoid ----------------
__global__ __launch_bounds__(256) void k_head(const float* __restrict__ hs0, const float* __restrict__ hs1,
                                              const float* __restrict__ hs2,
                                              const float* __restrict__ cw0, const float* __restrict__ cb0,
                                              const float* __restrict__ cw1, const float* __restrict__ cb1,
                                              const float* __restrict__ cw2, const float* __restrict__ cb2,
                                              const float* __restrict__ mw0, const float* __restrict__ mb0,
                                              const float* __restrict__ mw1, const float* __restrict__ mb1,
                                              const float* __restrict__ mw2, const float* __restrict__ mb2,
                                              const float* __restrict__ mw3, const float* __restrict__ mb3,
                                              const float* __restrict__ mw4, const float* __restrict__ mb4,
                                              const float* __restrict__ sw, const float* __restrict__ sb,
                                              float* __restrict__ out) {
  __shared__ float hi[2240];  // 20*64 + 20*32 + 20*16
  __shared__ float hj[2240];
  __shared__ float sim[400];
  __shared__ float simr[100];
  __shared__ float feat[2400];
  __shared__ float red[256];
  __shared__ float mbuf[60];
  const int b = blockIdx.x, t = threadIdx.x;

  for (int k = t; k < 1280; k += 256) {
    hi[k] = hs0[(size_t)(0 * BB + b) * 1280 + k];
    hj[k] = hs0[(size_t)(1 * BB + b) * 1280 + k];
  }
  for (int k = t; k < 640; k += 256) {
    hi[1280 + k] = hs1[(size_t)(0 * BB + b) * 640 + k];
    hj[1280 + k] = hs1[(size_t)(1 * BB + b) * 640 + k];
  }
  for (int k = t; k < 320; k += 256) {
    hi[1920 + k] = hs2[(size_t)(0 * BB + b) * 320 + k];
    hj[1920 + k] = hs2[(size_t)(1 * BB + b) * 320 + k];
  }
  __syncthreads();

  const int Fs[3] = {64, 32, 16};
  const int HOFF[3] = {0, 1280, 1920};
  const float* CW[3] = {cw0, cw1, cw2};
  const float* CB[3] = {cb0, cb1, cb2};

  for (int li = 0; li < 3; ++li) {
    const int F = Fs[li];
    const float* Hi = hi + HOFF[li];
    const float* Hj = hj + HOFF[li];
    for (int p = t; p < 400; p += 256) {
      int r = p / 20, cq = p % 20;
      float a = 0.0f;
      for (int d = 0; d < F; ++d) a += Hi[r * F + d] * Hj[cq * F + d];
      sim[p] = a;
    }
    __syncthreads();
    if (t < 100) {
      int oy = t / 10, ox = t % 10;
      float cy = (oy + 0.5f) * (512.0f / 10.0f) - 0.5f;
      float cx = (ox + 0.5f) * (512.0f / 10.0f) - 0.5f;
      float fy = cy - floorf(cy);
      float fx = cx - floorf(cx);
      int r0 = 2 * oy, c0 = 2 * ox;
      float s00 = sim[r0 * 20 + c0], s01 = sim[r0 * 20 + c0 + 1];
      float s10 = sim[(r0 + 1) * 20 + c0], s11 = sim[(r0 + 1) * 20 + c0 + 1];
      simr[t] = (1.0f - fy) * ((1.0f - fx) * s00 + fx * s01) + fy * ((1.0f - fx) * s10 + fx * s11);
    }
    __syncthreads();
    const float* cw = CW[li];
    const float* cb = CB[li];
    for (int idx = t; idx < 800; idx += 256) {
      int cch = idx / 100, rem = idx % 100, y = rem / 10, x = rem % 10;
      float a = cb[cch];
#pragma unroll
      for (int ky = 0; ky < 3; ++ky) {
#pragma unroll
        for (int kx = 0; kx < 3; ++kx) {
          int iy = y + ky - 1, ix = x + kx - 1;
          if (iy >= 0 && iy < 10 && ix >= 0 && ix < 10)
            a += cw[cch * 9 + ky * 3 + kx] * simr[iy * 10 + ix];
        }
      }
      feat[li * 800 + idx] = fmaxf(a, 0.0f);
    }
    __syncthreads();
  }

  // MLP0: 2400 -> 32, 8 partial sums per output
  {
    int f = t & 31, part = t >> 5;
    float a = 0.0f;
    int k0 = part * 300;
    for (int k = k0; k < k0 + 300; ++k) a += feat[k] * mw0[k * 32 + f];
    red[t] = a;
    __syncthreads();
    if (t < 32) {
      float s = mb0[t];
#pragma unroll
      for (int p = 0; p < 8; ++p) s += red[p * 32 + t];
      mbuf[t] = fmaxf(s, 0.0f);
    }
    __syncthreads();
  }
  if (t < 16) {
    float s = mb1[t];
    for (int k = 0; k < 32; ++k) s += mbuf[k] * mw1[k * 16 + t];
    mbuf[32 + t] = fmaxf(s, 0.0f);
  }
  __syncthreads();
  if (t < 8) {
    float s = mb2[t];
    for (int k = 0; k < 16; ++k) s += mbuf[32 + k] * mw2[k * 8 + t];
    mbuf[48 + t] = fmaxf(s, 0.0f);
  }
  __syncthreads();
  if (t < 4) {
    float s = mb3[t];
    for (int k = 0; k < 8; ++k) s += mbuf[48 + k] * mw3[k * 4 + t];
    mbuf[56 + t] = fmaxf(s, 0.0f);
  }
  __syncthreads();
  if (t == 0) {
    float s = mb4[0];
    for (int k = 0; k < 4; ++k) s += mbuf[56 + k] * mw4[k];
    s = fmaxf(s, 0.0f);
    float z = s * sw[0] + sb[0];
    out[b] = 1.0f / (1.0f + expf(-z));
  }
}

extern "C" void kernel_launch(void* const* d_in, const int* in_sizes, int n_in,
                              void* d_out, int out_size, void* d_ws, size_t ws_size,
                              hipStream_t stream) {
  (void)in_sizes; (void)n_in; (void)out_size; (void)ws_size;
  const float* x_i = (const float*)d_in[0];
  const float* x_j = (const float*)d_in[1];
  const float* gw0 = (const float*)d_in[2];
  const float* gb0 = (const float*)d_in[3];
  const float* gw1 = (const float*)d_in[4];
  const float* gb1 = (const float*)d_in[5];
  const float* gw2 = (const float*)d_in[6];
  const float* gb2 = (const float*)d_in[7];
  const float* cw0 = (const float*)d_in[8];
  const float* cb0 = (const float*)d_in[9];
  const float* cw1 = (const float*)d_in[10];
  const float* cb1 = (const float*)d_in[11];
  const float* cw2 = (const float*)d_in[12];
  const float* cb2 = (const float*)d_in[13];
  const float* mw0 = (const float*)d_in[14];
  const float* mb0 = (const float*)d_in[15];
  const float* mw1 = (const float*)d_in[16];
  const float* mb1 = (const float*)d_in[17];
  const float* mw2 = (const float*)d_in[18];
  const float* mb2 = (const float*)d_in[19];
  const float* mw3 = (const float*)d_in[20];
  const float* mb3 = (const float*)d_in[21];
  const float* mw4 = (const float*)d_in[22];
  const float* mb4 = (const float*)d_in[23];
  const float* scw = (const float*)d_in[24];
  const float* scb = (const float*)d_in[25];
  const int* ei = (const int*)d_in[26];
  const int* ej = (const int*)d_in[27];
  float* out = (float*)d_out;

  char* p = (char*)d_ws;
  auto take = [&](size_t bytes) {
    char* r = p;
    p += (bytes + 255) & ~(size_t)255;
    return r;
  };
  float* hs0 = (float*)take((size_t)2 * BB * 20 * 64 * 4);
  float* hs1 = (float*)take((size_t)2 * BB * 20 * 32 * 4);
  float* hs2 = (float*)take((size_t)2 * BB * 20 * 16 * 4);

  k_all<<<2 * BB, 512, 0, stream>>>(x_i, x_j, gw0, gb0, gw1, gb1, gw2, gb2,
                                    ei, ej, hs0, hs1, hs2);
  k_head<<<BB, 256, 0, stream>>>(hs0, hs1, hs2, cw0, cb0, cw1, cb1, cw2, cb2,
                                 mw0, mb0, mw1, mb1, mw2, mb2, mw3, mb3, mw4, mb4,
                                 scw, scb, out);
}

// Round 19
// 130.331 us; speedup vs baseline: 4.7393x; 1.0102x over previous
//
#include <hip/hip_runtime.h>
#include <hip/hip_fp16.h>

typedef float fvec4 __attribute__((ext_vector_type(4)));
typedef int ivec4 __attribute__((ext_vector_type(4)));

#define NN 65536      // total nodes per side (B*NPG)
#define EE 1048576    // edges per side (B*NPG*DEG)
#define BB 128
#define NPG 512
#define EPG 8192      // edges per graph (NPG*DEG)

__device__ __forceinline__ int pkrtz(float a, float b) {
  union { __half2 h; int i; } u; u.h = __floats2half2_rn(a, b); return u.i;
}
__device__ __forceinline__ float2 up2(int v) {
  union { int i; __half2 h; } u; u.i = v; return __half22float2(u.h);
}

// accumulate one 16B quad (8 f16) into two fvec4 f32 partial sums
#define ACCQ(SA, SB, w) { float2 f_; \
  f_ = up2((w)[0]); (SA)[0] += f_.x; (SA)[1] += f_.y; \
  f_ = up2((w)[1]); (SA)[2] += f_.x; (SA)[3] += f_.y; \
  f_ = up2((w)[2]); (SB)[0] += f_.x; (SB)[1] += f_.y; \
  f_ = up2((w)[3]); (SB)[2] += f_.x; (SB)[3] += f_.y; }

// gather 32 feats (4 quads) into S[8], unrolled x2 with grouped loads
#define GATHER32(buf, S, startE, countE) { \
  int e_ = (startE); const int end_ = (startE) + (countE); \
  for (; e_ + 2 <= end_; e_ += 2) { \
    const int Ka_ = sids[e_], Kb_ = sids[e_ + 1]; \
    const ivec4 a0_ = (buf)[Ka_], a1_ = (buf)[Ka_ ^ 1], a2_ = (buf)[Ka_ ^ 2], a3_ = (buf)[Ka_ ^ 3]; \
    const ivec4 b0_ = (buf)[Kb_], b1_ = (buf)[Kb_ ^ 1], b2_ = (buf)[Kb_ ^ 2], b3_ = (buf)[Kb_ ^ 3]; \
    ACCQ((S)[0], (S)[1], a0_) ACCQ((S)[2], (S)[3], a1_) ACCQ((S)[4], (S)[5], a2_) ACCQ((S)[6], (S)[7], a3_) \
    ACCQ((S)[0], (S)[1], b0_) ACCQ((S)[2], (S)[3], b1_) ACCQ((S)[4], (S)[5], b2_) ACCQ((S)[6], (S)[7], b3_) \
  } \
  if (e_ < end_) { \
    const int Ka_ = sids[e_]; \
    const ivec4 a0_ = (buf)[Ka_], a1_ = (buf)[Ka_ ^ 1], a2_ = (buf)[Ka_ ^ 2], a3_ = (buf)[Ka_ ^ 3]; \
    ACCQ((S)[0], (S)[1], a0_) ACCQ((S)[2], (S)[3], a1_) ACCQ((S)[4], (S)[5], a2_) ACCQ((S)[6], (S)[7], a3_) \
  } }

// ---------------- one block per (side, graph): CSR build + degree-sort + 3 GCN layers ----------------
// f16 messages, f32 accumulation. Row r = 4 quads (64B); quad q at index key^q with
// key = (r<<2) | ((r>>1)&3) -> for fixed q, random r spreads over all 8 bank groups.
// sids[] holds pre-swizzled u16 keys, CSR-bucketed by dst.
__global__ __launch_bounds__(512)
void k_all(const float* __restrict__ x_i, const float* __restrict__ x_j,
           const float* __restrict__ gw0, const float* __restrict__ gb0,
           const float* __restrict__ gw1, const float* __restrict__ gb1,
           const float* __restrict__ gw2, const float* __restrict__ gb2,
           const int* __restrict__ ei, const int* __restrict__ ej,
           float* __restrict__ hs0, float* __restrict__ hs1, float* __restrict__ hs2) {
  __shared__ ivec4 bufA[NPG * 4];         // 32 KB (aliases dsts staging in prep)
  __shared__ ivec4 bufB[NPG * 4];         // 32 KB
  __shared__ unsigned short sids[EPG];    // 16 KB: pre-swizzled keys
  __shared__ int cnt[NPG];
  __shared__ int posb[NPG];
  __shared__ int nodeOf[NPG];
  __shared__ int bins[64];
  __shared__ int binpos[64];
  __shared__ int wsum[8];
  unsigned short* const dsts = reinterpret_cast<unsigned short*>(bufA);  // prep-only

  const int side = blockIdx.x >> 7;
  const int g = blockIdx.x & 127;
  const float* __restrict__ x = side ? x_j : x_i;
  const int* __restrict__ eidx = side ? ej : ei;
  const int v = threadIdx.x;
  const int base = g * NPG;
  const int ebase = g * EPG;

  // ---- degree count ----
  cnt[v] = 0;
  if (v < 64) bins[v] = 0;
  __syncthreads();
  for (int k = v; k < EPG; k += 512) {
    int d = eidx[EE + ebase + k] - base;
    dsts[k] = (unsigned short)d;
    atomicAdd(&cnt[d], 1);
  }
  __syncthreads();

  // ---- scan over 512 counts + degree histogram ----
  const int count = cnt[v];
  const int deg = count > 63 ? 63 : count;
  atomicAdd(&bins[deg], 1);
  int xa = count;
  const int lane = v & 63;
#pragma unroll
  for (int d = 1; d < 64; d <<= 1) {
    int y = __shfl_up(xa, d, 64);
    if (lane >= d) xa += y;
  }
  const int wid = v >> 6;
  if (lane == 63) wsum[wid] = xa;
  __syncthreads();
  if (v < 64) {
    if (v == 0) {
      int a = 0;
#pragma unroll
      for (int i = 0; i < 8; ++i) { int tv = wsum[i]; wsum[i] = a; a += tv; }
    }
    int c = bins[v];
    int xb = c;
#pragma unroll
    for (int d = 1; d < 64; d <<= 1) {
      int y = __shfl_up(xb, d, 64);
      if (v >= d) xb += y;
    }
    binpos[v] = xb - c;
  }
  __syncthreads();
  const int start_v = xa - count + wsum[wid];
  posb[v] = start_v;
  {
    int rank = atomicAdd(&binpos[deg], 1);
    nodeOf[rank] = v;
  }
  __syncthreads();

  // ---- CSR fill with pre-swizzled u16 keys ----
  for (int k = v; k < EPG; k += 512) {
    int lv = eidx[ebase + k] - base;
    int p = atomicAdd(&posb[dsts[k]], 1);
    sids[p] = (unsigned short)((lv << 2) | ((lv >> 1) & 3));
  }
  __syncthreads();

  // ---- this thread owns node = nodeOf[v] (wave-uniform degrees) ----
  const int node = nodeOf[v];
  const int ncount = cnt[node];
  const int nstart = posb[node] - ncount;
  const float inv_v = rsqrtf((float)ncount + 1.0f);
  const int myKey = (node << 2) | ((node >> 1) & 3);

  constexpr int srows[20] = {25, 26, 76, 77, 127, 128, 178, 179, 229, 230,
                             281, 282, 332, 333, 383, 384, 434, 435, 485, 486};
  int slot = -1;
#pragma unroll
  for (int i = 0; i < 20; ++i)
    if (node == srows[i]) slot = i;
  const int hb = (side * BB + g) * 20;

  // ---- layer 0: full xW0 row in one streaming pass over x ----
  fvec4 a0[16];
#pragma unroll
  for (int q = 0; q < 16; ++q) a0[q] = fvec4{0.f, 0.f, 0.f, 0.f};
  {
    const fvec4* xv = reinterpret_cast<const fvec4*>(x + (size_t)(base + node) * 64);
#pragma unroll 1
    for (int k16 = 0; k16 < 4; ++k16) {
      fvec4 xq[4];
#pragma unroll
      for (int u = 0; u < 4; ++u) xq[u] = xv[4 * k16 + u];
#pragma unroll
      for (int u = 0; u < 4; ++u) {
#pragma unroll
        for (int j = 0; j < 4; ++j) {
          const float xk = xq[u][j];
          const fvec4* wr = reinterpret_cast<const fvec4*>(gw0 + (size_t)(16 * k16 + 4 * u + j) * 64);
#pragma unroll
          for (int q = 0; q < 16; ++q) a0[q] += xk * wr[q];
        }
      }
    }
  }

  // ---- L0: scale + publish BOTH halves now (a0 dies here); s = exact self for half A ----
  fvec4 s[8];
#pragma unroll
  for (int q = 0; q < 8; ++q) s[q] = a0[q] * inv_v;
#pragma unroll
  for (int q_ = 0; q_ < 4; ++q_) {
    ivec4 wA, wB;
    wA[0] = pkrtz(s[2 * q_][0], s[2 * q_][1]);
    wA[1] = pkrtz(s[2 * q_][2], s[2 * q_][3]);
    wA[2] = pkrtz(s[2 * q_ + 1][0], s[2 * q_ + 1][1]);
    wA[3] = pkrtz(s[2 * q_ + 1][2], s[2 * q_ + 1][3]);
    fvec4 b0 = a0[8 + 2 * q_] * inv_v;
    fvec4 b1 = a0[8 + 2 * q_ + 1] * inv_v;
    wB[0] = pkrtz(b0[0], b0[1]); wB[1] = pkrtz(b0[2], b0[3]);
    wB[2] = pkrtz(b1[0], b1[1]); wB[3] = pkrtz(b1[2], b1[3]);
    bufA[myKey ^ q_] = wA;
    bufB[myKey ^ q_] = wB;
  }
  __syncthreads();

  // ---- L0a gather ----
  GATHER32(bufA, s, nstart, ncount)

  // ---- L0a epilogue: h0a = relu(s*inv + b); fold y1 += h0a * W1[0:32,:] ----
  fvec4 y1[8];
#pragma unroll
  for (int p = 0; p < 8; ++p) y1[p] = fvec4{0.f, 0.f, 0.f, 0.f};
  {
    const fvec4* gb0v = reinterpret_cast<const fvec4*>(gb0);
    fvec4* hp = reinterpret_cast<fvec4*>(hs0 + ((size_t)hb + slot) * 64);
#pragma unroll
    for (int q = 0; q < 8; ++q) {
      fvec4 o = s[q] * inv_v + gb0v[q];
#pragma unroll
      for (int j = 0; j < 4; ++j) o[j] = fmaxf(o[j], 0.f);
      if (slot >= 0) hp[q] = o;
#pragma unroll
      for (int j = 0; j < 4; ++j) {
        const float hf = o[j];
        const fvec4* wr = reinterpret_cast<const fvec4*>(gw1 + (size_t)(q * 4 + j) * 32);
#pragma unroll
        for (int p = 0; p < 8; ++p) y1[p] += hf * wr[p];
      }
    }
  }

  // ---- L0b: re-init self from own published row (one extra f16 rounding), gather ----
  fvec4 sB[8];
#pragma unroll
  for (int q = 0; q < 8; ++q) sB[q] = fvec4{0.f, 0.f, 0.f, 0.f};
  {
    const ivec4 w0 = bufB[myKey], w1 = bufB[myKey ^ 1], w2 = bufB[myKey ^ 2], w3 = bufB[myKey ^ 3];
    ACCQ(sB[0], sB[1], w0) ACCQ(sB[2], sB[3], w1) ACCQ(sB[4], sB[5], w2) ACCQ(sB[6], sB[7], w3)
  }
  GATHER32(bufB, sB, nstart, ncount)

  // ---- L0b epilogue: fold y1 += h0b * W1[32:64,:] ----
  {
    const fvec4* gb0v = reinterpret_cast<const fvec4*>(gb0);
    fvec4* hp = reinterpret_cast<fvec4*>(hs0 + ((size_t)hb + slot) * 64);
#pragma unroll
    for (int q = 0; q < 8; ++q) {
      fvec4 o = sB[q] * inv_v + gb0v[8 + q];
#pragma unroll
      for (int j = 0; j < 4; ++j) o[j] = fmaxf(o[j], 0.f);
      if (slot >= 0) hp[8 + q] = o;
#pragma unroll
      for (int j = 0; j < 4; ++j) {
        const float hf = o[j];
        const fvec4* wr = reinterpret_cast<const fvec4*>(gw1 + (size_t)((8 + q) * 4 + j) * 32);
#pragma unroll
        for (int p = 0; p < 8; ++p) y1[p] += hf * wr[p];
      }
    }
  }
  __syncthreads();  // all L0a gathers done (bufA free for L1)

  // ---- L1: scale + publish y1 into bufA ----
  fvec4 s1[8];
#pragma unroll
  for (int q = 0; q < 8; ++q) s1[q] = y1[q] * inv_v;
#pragma unroll
  for (int q_ = 0; q_ < 4; ++q_) {
    ivec4 w_;
    w_[0] = pkrtz(s1[2 * q_][0], s1[2 * q_][1]);
    w_[1] = pkrtz(s1[2 * q_][2], s1[2 * q_][3]);
    w_[2] = pkrtz(s1[2 * q_ + 1][0], s1[2 * q_ + 1][1]);
    w_[3] = pkrtz(s1[2 * q_ + 1][2], s1[2 * q_ + 1][3]);
    bufA[myKey ^ q_] = w_;
  }
  __syncthreads();  // pub L1 visible; all L0b gathers done (bufB free)

  // ---- L1 gather ----
  GATHER32(bufA, s1, nstart, ncount)

  // ---- L1 epilogue: h1 = relu(...); fold y2 = h1*W2; hs1 ----
  fvec4 y2[4];
#pragma unroll
  for (int p = 0; p < 4; ++p) y2[p] = fvec4{0.f, 0.f, 0.f, 0.f};
  {
    const fvec4* gb1v = reinterpret_cast<const fvec4*>(gb1);
    fvec4* hp = reinterpret_cast<fvec4*>(hs1 + ((size_t)hb + slot) * 32);
#pragma unroll
    for (int q = 0; q < 8; ++q) {
      fvec4 o = s1[q] * inv_v + gb1v[q];
#pragma unroll
      for (int j = 0; j < 4; ++j) o[j] = fmaxf(o[j], 0.f);
      if (slot >= 0) hp[q] = o;
#pragma unroll
      for (int j = 0; j < 4; ++j) {
        const float hf = o[j];
        const fvec4* wr = reinterpret_cast<const fvec4*>(gw2 + (size_t)(q * 4 + j) * 16);
#pragma unroll
        for (int p = 0; p < 4; ++p) y2[p] += hf * wr[p];
      }
    }
  }

  // ---- L2: scale + publish y2 (16 feats = 2 quads) into bufB ----
  {
    fvec4 q0 = y2[0] * inv_v, q1 = y2[1] * inv_v, q2 = y2[2] * inv_v, q3 = y2[3] * inv_v;
    ivec4 w0, w1;
    w0[0] = pkrtz(q0[0], q0[1]); w0[1] = pkrtz(q0[2], q0[3]);
    w0[2] = pkrtz(q1[0], q1[1]); w0[3] = pkrtz(q1[2], q1[3]);
    w1[0] = pkrtz(q2[0], q2[1]); w1[1] = pkrtz(q2[2], q2[3]);
    w1[2] = pkrtz(q3[0], q3[1]); w1[3] = pkrtz(q3[2], q3[3]);
    bufB[myKey] = w0;
    bufB[myKey ^ 1] = w1;
  }
  __syncthreads();  // pub L2 visible; all L1 gathers done

  // ---- L2 gather: COMPACTED — threads 0..19 each take one sampled node ----
  if (v < 20) {
    const int n = srows[v];
    const int ccount = cnt[n];
    const int cstart = posb[n] - ccount;
    const float cinv = rsqrtf((float)ccount + 1.0f);
    const int ckey = (n << 2) | ((n >> 1) & 3);
    fvec4 s2[4];
#pragma unroll
    for (int q = 0; q < 4; ++q) s2[q] = fvec4{0.f, 0.f, 0.f, 0.f};
    {  // self message (f16-rounded)
      const ivec4 w0 = bufB[ckey], w1 = bufB[ckey ^ 1];
      ACCQ(s2[0], s2[1], w0) ACCQ(s2[2], s2[3], w1)
    }
    int e = cstart;
    const int end = cstart + ccount;
    for (; e + 2 <= end; e += 2) {
      const int Ka = sids[e], Kb = sids[e + 1];
      const ivec4 a0_ = bufB[Ka], a1_ = bufB[Ka ^ 1];
      const ivec4 b0_ = bufB[Kb], b1_ = bufB[Kb ^ 1];
      ACCQ(s2[0], s2[1], a0_) ACCQ(s2[2], s2[3], a1_)
      ACCQ(s2[0], s2[1], b0_) ACCQ(s2[2], s2[3], b1_)
    }
    if (e < end) {
      const int Ka = sids[e];
      const ivec4 a0_ = bufB[Ka], a1_ = bufB[Ka ^ 1];
      ACCQ(s2[0], s2[1], a0_) ACCQ(s2[2], s2[3], a1_)
    }
    const fvec4* gb2v = reinterpret_cast<const fvec4*>(gb2);
    fvec4* hp = reinterpret_cast<fvec4*>(hs2 + ((size_t)hb + v) * 16);
#pragma unroll
    for (int q = 0; q < 4; ++q) hp[q] = s2[q] * cinv + gb2v[q];
  }
}

// ---------------- head: sampled sim -> bilinear 10x10 -> conv3x3(1->8) -> MLP -> sigmoid ----------------
__global__ __launch_bounds__(256) void k_head(const float* __restrict__ hs0, const float* __restrict__ hs1,
                                              const float* __restrict__ hs2,
                                              const float* __restrict__ cw0, const float* __restrict__ cb0,
                                              const float* __restrict__ cw1, const float* __restrict__ cb1,
                                              const float* __restrict__ cw2, const float* __restrict__ cb2,
                                              const float* __restrict__ mw0, const float* __restrict__ mb0,
                                              const float* __restrict__ mw1, const float* __restrict__ mb1,
                                              const float* __restrict__ mw2, const float* __restrict__ mb2,
                                              const float* __restrict__ mw3, const float* __restrict__ mb3,
                                              const float* __restrict__ mw4, const float* __restrict__ mb4,
                                              const float* __restrict__ sw, const float* __restrict__ sb,
                                              float* __restrict__ out) {
  __shared__ float hi[2240];  // 20*64 + 20*32 + 20*16
  __shared__ float hj[2240];
  __shared__ float sim[400];
  __shared__ float simr[100];
  __shared__ float feat[2400];
  __shared__ float red[256];
  __shared__ float mbuf[60];
  const int b = blockIdx.x, t = threadIdx.x;

  for (int k = t; k < 1280; k += 256) {
    hi[k] = hs0[(size_t)(0 * BB + b) * 1280 + k];
    hj[k] = hs0[(size_t)(1 * BB + b) * 1280 + k];
  }
  for (int k = t; k < 640; k += 256) {
    hi[1280 + k] = hs1[(size_t)(0 * BB + b) * 640 + k];
    hj[1280 + k] = hs1[(size_t)(1 * BB + b) * 640 + k];
  }
  for (int k = t; k < 320; k += 256) {
    hi[1920 + k] = hs2[(size_t)(0 * BB + b) * 320 + k];
    hj[1920 + k] = hs2[(size_t)(1 * BB + b) * 320 + k];
  }
  __syncthreads();

  const int Fs[3] = {64, 32, 16};
  const int HOFF[3] = {0, 1280, 1920};
  const float* CW[3] = {cw0, cw1, cw2};
  const float* CB[3] = {cb0, cb1, cb2};

  for (int li = 0; li < 3; ++li) {
    const int F = Fs[li];
    const float* Hi = hi + HOFF[li];
    const float* Hj = hj + HOFF[li];
    for (int p = t; p < 400; p += 256) {
      int r = p / 20, cq = p % 20;
      float a = 0.0f;
      for (int d = 0; d < F; ++d) a += Hi[r * F + d] * Hj[cq * F + d];
      sim[p] = a;
    }
    __syncthreads();
    if (t < 100) {
      int oy = t / 10, ox = t % 10;
      float cy = (oy + 0.5f) * (512.0f / 10.0f) - 0.5f;
      float cx = (ox + 0.5f) * (512.0f / 10.0f) - 0.5f;
      float fy = cy - floorf(cy);
      float fx = cx - floorf(cx);
      int r0 = 2 * oy, c0 = 2 * ox;
      float s00 = sim[r0 * 20 + c0], s01 = sim[r0 * 20 + c0 + 1];
      float s10 = sim[(r0 + 1) * 20 + c0], s11 = sim[(r0 + 1) * 20 + c0 + 1];
      simr[t] = (1.0f - fy) * ((1.0f - fx) * s00 + fx * s01) + fy * ((1.0f - fx) * s10 + fx * s11);
    }
    __syncthreads();
    const float* cw = CW[li];
    const float* cb = CB[li];
    for (int idx = t; idx < 800; idx += 256) {
      int cch = idx / 100, rem = idx % 100, y = rem / 10, x = rem % 10;
      float a = cb[cch];
#pragma unroll
      for (int ky = 0; ky < 3; ++ky) {
#pragma unroll
        for (int kx = 0; kx < 3; ++kx) {
          int iy = y + ky - 1, ix = x + kx - 1;
          if (iy >= 0 && iy < 10 && ix >= 0 && ix < 10)
            a += cw[cch * 9 + ky * 3 + kx] * simr[iy * 10 + ix];
        }
      }
      feat[li * 800 + idx] = fmaxf(a, 0.0f);
    }
    __syncthreads();
  }

  // MLP0: 2400 -> 32, 8 partial sums per output
  {
    int f = t & 31, part = t >> 5;
    float a = 0.0f;
    int k0 = part * 300;
    for (int k = k0; k < k0 + 300; ++k) a += feat[k] * mw0[k * 32 + f];
    red[t] = a;
    __syncthreads();
    if (t < 32) {
      float s = mb0[t];
#pragma unroll
      for (int p = 0; p < 8; ++p) s += red[p * 32 + t];
      mbuf[t] = fmaxf(s, 0.0f);
    }
    __syncthreads();
  }
  if (t < 16) {
    float s = mb1[t];
    for (int k = 0; k < 32; ++k) s += mbuf[k] * mw1[k * 16 + t];
    mbuf[32 + t] = fmaxf(s, 0.0f);
  }
  __syncthreads();
  if (t < 8) {
    float s = mb2[t];
    for (int k = 0; k < 16; ++k) s += mbuf[32 + k] * mw2[k * 8 + t];
    mbuf[48 + t] = fmaxf(s, 0.0f);
  }
  __syncthreads();
  if (t < 4) {
    float s = mb3[t];
    for (int k = 0; k < 8; ++k) s += mbuf[48 + k] * mw3[k * 4 + t];
    mbuf[56 + t] = fmaxf(s, 0.0f);
  }
  __syncthreads();
  if (t == 0) {
    float s = mb4[0];
    for (int k = 0; k < 4; ++k) s += mbuf[56 + k] * mw4[k];
    s = fmaxf(s, 0.0f);
    float z = s * sw[0] + sb[0];
    out[b] = 1.0f / (1.0f + expf(-z));
  }
}

extern "C" void kernel_launch(void* const* d_in, const int* in_sizes, int n_in,
                              void* d_out, int out_size, void* d_ws, size_t ws_size,
                              hipStream_t stream) {
  (void)in_sizes; (void)n_in; (void)out_size; (void)ws_size;
  const float* x_i = (const float*)d_in[0];
  const float* x_j = (const float*)d_in[1];
  const float* gw0 = (const float*)d_in[2];
  const float* gb0 = (const float*)d_in[3];
  const float* gw1 = (const float*)d_in[4];
  const float* gb1 = (const float*)d_in[5];
  const float* gw2 = (const float*)d_in[6];
  const float* gb2 = (const float*)d_in[7];
  const float* cw0 = (const float*)d_in[8];
  const float* cb0 = (const float*)d_in[9];
  const float* cw1 = (const float*)d_in[10];
  const float* cb1 = (const float*)d_in[11];
  const float* cw2 = (const float*)d_in[12];
  const float* cb2 = (const float*)d_in[13];
  const float* mw0 = (const float*)d_in[14];
  const float* mb0 = (const float*)d_in[15];
  const float* mw1 = (const float*)d_in[16];
  const float* mb1 = (const float*)d_in[17];
  const float* mw2 = (const float*)d_in[18];
  const float* mb2 = (const float*)d_in[19];
  const float* mw3 = (const float*)d_in[20];
  const float* mb3 = (const float*)d_in[21];
  const float* mw4 = (const float*)d_in[22];
  const float* mb4 = (const float*)d_in[23];
  const float* scw = (const float*)d_in[24];
  const float* scb = (const float*)d_in[25];
  const int* ei = (const int*)d_in[26];
  const int* ej = (const int*)d_in[27];
  float* out = (float*)d_out;

  char* p = (char*)d_ws;
  auto take = [&](size_t bytes) {
    char* r = p;
    p += (bytes + 255) & ~(size_t)255;
    return r;
  };
  float* hs0 = (float*)take((size_t)2 * BB * 20 * 64 * 4);
  float* hs1 = (float*)take((size_t)2 * BB * 20 * 32 * 4);
  float* hs2 = (float*)take((size_t)2 * BB * 20 * 16 * 4);

  k_all<<<2 * BB, 512, 0, stream>>>(x_i, x_j, gw0, gb0, gw1, gb1, gw2, gb2,
                                    ei, ej, hs0, hs1, hs2);
  k_head<<<BB, 256, 0, stream>>>(hs0, hs1, hs2, cw0, cb0, cw1, cb1, cw2, cb2,
                                 mw0, mb0, mw1, mb1, mw2, mb2, mw3, mb3, mw4, mb4,
                                 scw, scb, out);
}

// Round 21
// 121.645 us; speedup vs baseline: 5.0777x; 1.0714x over previous
//
#include <hip/hip_runtime.h>
#include <hip/hip_fp16.h>

typedef float fvec4 __attribute__((ext_vector_type(4)));
typedef int ivec4 __attribute__((ext_vector_type(4)));

#define NN 65536      // total nodes per side (B*NPG)
#define EE 1048576    // edges per side (B*NPG*DEG)
#define BB 128
#define NPG 512
#define EPG 8192      // edges per graph (NPG*DEG)

__device__ __forceinline__ int pkrtz(float a, float b) {
  union { __half2 h; int i; } u; u.h = __floats2half2_rn(a, b); return u.i;
}
__device__ __forceinline__ float2 up2(int v) {
  union { int i; __half2 h; } u; u.i = v; return __half22float2(u.h);
}

// accumulate one 16B quad (8 f16) into two fvec4 f32 partial sums
#define ACCQ(SA, SB, w) { float2 f_; \
  f_ = up2((w)[0]); (SA)[0] += f_.x; (SA)[1] += f_.y; \
  f_ = up2((w)[1]); (SA)[2] += f_.x; (SA)[3] += f_.y; \
  f_ = up2((w)[2]); (SB)[0] += f_.x; (SB)[1] += f_.y; \
  f_ = up2((w)[3]); (SB)[2] += f_.x; (SB)[3] += f_.y; }

__device__ __forceinline__ int slot_of(int node) {
  constexpr int srows[20] = {25, 26, 76, 77, 127, 128, 178, 179, 229, 230,
                             281, 282, 332, 333, 383, 384, 434, 435, 485, 486};
  int slot = -1;
#pragma unroll
  for (int i = 0; i < 20; ++i)
    if (node == srows[i]) slot = i;
  return slot;
}
__constant__ int c_srows[20] = {25, 26, 76, 77, 127, 128, 178, 179, 229, 230,
                                281, 282, 332, 333, 383, 384, 434, 435, 485, 486};

// ================= kA: per (side,graph,half): CSR build + L0 half + y1 partial =================
// 512 blocks x 512 threads; LDS ~52KB -> 2 blocks/CU (16 waves/CU).
// msg row r = 4 f16 quads; quad q at key^q, key = (r<<2)|((r>>1)&3) (bank-group uniform).
__global__ __launch_bounds__(512)
void kA(const float* __restrict__ x_i, const float* __restrict__ x_j,
        const float* __restrict__ gw0, const float* __restrict__ gb0,
        const float* __restrict__ gw1,
        const int* __restrict__ ei, const int* __restrict__ ej,
        unsigned short* __restrict__ sidsG, unsigned int* __restrict__ packG,
        float* __restrict__ hs0, unsigned int* __restrict__ y1G) {
  __shared__ ivec4 buf[NPG * 4];          // 32 KB (aliases dsts staging in prep)
  __shared__ unsigned short sids[EPG];    // 16 KB: raw local src ids
  __shared__ int cnt[NPG];
  __shared__ int posb[NPG];
  __shared__ int wsum[8];
  unsigned short* const dsts = reinterpret_cast<unsigned short*>(buf);  // prep-only

  const int bid = blockIdx.x;
  const int half = bid & 1;
  const int sg = bid >> 1;                 // 0..255 = side*128+g
  const int side = sg >> 7, g = sg & 127;
  const float* __restrict__ x = side ? x_j : x_i;
  const int* __restrict__ eidx = side ? ej : ei;
  const int v = threadIdx.x;
  const int base = g * NPG, ebase = g * EPG;

  // ---- degree count ----
  cnt[v] = 0;
  __syncthreads();
  for (int k = v; k < EPG; k += 512) {
    int d = eidx[EE + ebase + k] - base;
    dsts[k] = (unsigned short)d;
    atomicAdd(&cnt[d], 1);
  }
  __syncthreads();

  // ---- exclusive scan over 512 counts ----
  const int count = cnt[v];
  int xa = count;
  const int lane = v & 63;
#pragma unroll
  for (int d = 1; d < 64; d <<= 1) {
    int y = __shfl_up(xa, d, 64);
    if (lane >= d) xa += y;
  }
  const int wid = v >> 6;
  if (lane == 63) wsum[wid] = xa;
  __syncthreads();
  if (v == 0) {
    int a = 0;
#pragma unroll
    for (int i = 0; i < 8; ++i) { int tv = wsum[i]; wsum[i] = a; a += tv; }
  }
  __syncthreads();
  posb[v] = xa - count + wsum[wid];
  __syncthreads();

  // ---- CSR fill (bucket by dst), raw ids ----
  for (int k = v; k < EPG; k += 512) {
    int lv = eidx[ebase + k] - base;
    int p = atomicAdd(&posb[dsts[k]], 1);
    sids[p] = (unsigned short)lv;
  }

  // ---- L0 half-GEMM: a0 = x_row @ W0[:, half*32 : half*32+32] (no LDS touched) ----
  fvec4 a0[8];
#pragma unroll
  for (int q = 0; q < 8; ++q) a0[q] = fvec4{0.f, 0.f, 0.f, 0.f};
  {
    const fvec4* xv = reinterpret_cast<const fvec4*>(x + (size_t)(base + v) * 64);
    const float* w0h = gw0 + half * 32;
#pragma unroll 1
    for (int k16 = 0; k16 < 4; ++k16) {
      fvec4 xq[4];
#pragma unroll
      for (int u = 0; u < 4; ++u) xq[u] = xv[4 * k16 + u];
#pragma unroll
      for (int u = 0; u < 4; ++u) {
#pragma unroll
        for (int j = 0; j < 4; ++j) {
          const float xk = xq[u][j];
          const fvec4* wr = reinterpret_cast<const fvec4*>(w0h + (size_t)(16 * k16 + 4 * u + j) * 64);
#pragma unroll
          for (int q = 0; q < 8; ++q) a0[q] += xk * wr[q];
        }
      }
    }
  }
  __syncthreads();  // fill complete; dsts dead -> buf reusable

  // ---- export CSR (half 0 only) + publish own messages ----
  const int sgE = sg * EPG;
  if (half == 0) {
    const int* srcI = reinterpret_cast<const int*>(sids);
    int* dstI = reinterpret_cast<int*>(sidsG + sgE);
    for (int k = v; k < EPG / 2; k += 512) dstI[k] = srcI[k];
    packG[sg * NPG + v] = ((unsigned int)(posb[v] - count) << 16) | (unsigned int)count;
  }
  const float inv_v = rsqrtf((float)count + 1.0f);
  const int myKey = (v << 2) | ((v >> 1) & 3);
  fvec4 s[8];
#pragma unroll
  for (int q = 0; q < 8; ++q) s[q] = a0[q] * inv_v;
#pragma unroll
  for (int q_ = 0; q_ < 4; ++q_) {
    ivec4 w_;
    w_[0] = pkrtz(s[2 * q_][0], s[2 * q_][1]);
    w_[1] = pkrtz(s[2 * q_][2], s[2 * q_][3]);
    w_[2] = pkrtz(s[2 * q_ + 1][0], s[2 * q_ + 1][1]);
    w_[3] = pkrtz(s[2 * q_ + 1][2], s[2 * q_ + 1][3]);
    buf[myKey ^ q_] = w_;
  }
  __syncthreads();

  // ---- gather 32 feats (unroll x2, keys computed from raw ids) ----
  const int nstart = posb[v] - count;
  {
    int e = nstart;
    const int end = nstart + count;
    for (; e + 2 <= end; e += 2) {
      const int la = sids[e], lb = sids[e + 1];
      const int Ka = (la << 2) | ((la >> 1) & 3);
      const int Kb = (lb << 2) | ((lb >> 1) & 3);
      const ivec4 a0_ = buf[Ka], a1_ = buf[Ka ^ 1], a2_ = buf[Ka ^ 2], a3_ = buf[Ka ^ 3];
      const ivec4 b0_ = buf[Kb], b1_ = buf[Kb ^ 1], b2_ = buf[Kb ^ 2], b3_ = buf[Kb ^ 3];
      ACCQ(s[0], s[1], a0_) ACCQ(s[2], s[3], a1_) ACCQ(s[4], s[5], a2_) ACCQ(s[6], s[7], a3_)
      ACCQ(s[0], s[1], b0_) ACCQ(s[2], s[3], b1_) ACCQ(s[4], s[5], b2_) ACCQ(s[6], s[7], b3_)
    }
    if (e < end) {
      const int la = sids[e];
      const int Ka = (la << 2) | ((la >> 1) & 3);
      const ivec4 a0_ = buf[Ka], a1_ = buf[Ka ^ 1], a2_ = buf[Ka ^ 2], a3_ = buf[Ka ^ 3];
      ACCQ(s[0], s[1], a0_) ACCQ(s[2], s[3], a1_) ACCQ(s[4], s[5], a2_) ACCQ(s[6], s[7], a3_)
    }
  }

  // ---- epilogue: h0_half = relu(s*inv + b); hs0 slice; fold y1P = h0_half @ W1[half rows] ----
  const int slot = slot_of(v);
  const int hb = (side * BB + g) * 20;
  fvec4 y1P[8];
#pragma unroll
  for (int p = 0; p < 8; ++p) y1P[p] = fvec4{0.f, 0.f, 0.f, 0.f};
  {
    const fvec4* gb0v = reinterpret_cast<const fvec4*>(gb0 + half * 32);
    fvec4* hp = reinterpret_cast<fvec4*>(hs0 + ((size_t)hb + slot) * 64 + half * 32);
#pragma unroll
    for (int q = 0; q < 8; ++q) {
      fvec4 o = s[q] * inv_v + gb0v[q];
#pragma unroll
      for (int j = 0; j < 4; ++j) o[j] = fmaxf(o[j], 0.f);
      if (slot >= 0) hp[q] = o;
#pragma unroll
      for (int j = 0; j < 4; ++j) {
        const float hf = o[j];
        const fvec4* wr = reinterpret_cast<const fvec4*>(gw1 + (size_t)(half * 32 + q * 4 + j) * 32);
#pragma unroll
        for (int p = 0; p < 8; ++p) y1P[p] += hf * wr[p];
      }
    }
  }
  // ---- write y1 partial (32 f16 = 16 u32) ----
  {
    unsigned int* yp = y1G + ((size_t)(sg * 2 + half) * NPG + v) * 16;
#pragma unroll
    for (int w = 0; w < 16; ++w)
      yp[w] = (unsigned int)pkrtz(y1P[w >> 1][(w & 1) * 2], y1P[w >> 1][(w & 1) * 2 + 1]);
  }
}

// ================= kB: per (side,graph,half): L1 (16-feat slice) + y2 partial =================
__global__ __launch_bounds__(512)
void kB(const float* __restrict__ gb1, const float* __restrict__ gw2,
        const unsigned short* __restrict__ sidsG, const unsigned int* __restrict__ packG,
        const unsigned int* __restrict__ y1G,
        float* __restrict__ hs1, unsigned int* __restrict__ y2G) {
  __shared__ ivec4 buf[NPG * 2];          // 16 KB: msg rows of 2 quads
  __shared__ unsigned short sids[EPG];    // 16 KB
  const int bid = blockIdx.x;
  const int half = bid & 1;
  const int sg = bid >> 1;
  const int side = sg >> 7, g = sg & 127;
  const int v = threadIdx.x;

  {
    const int* srcI = reinterpret_cast<const int*>(sidsG + sg * EPG);
    int* dstI = reinterpret_cast<int*>(sids);
    for (int k = v; k < EPG / 2; k += 512) dstI[k] = srcI[k];
  }
  const unsigned int pack = packG[sg * NPG + v];
  const int count = (int)(pack & 0xffffu);
  const int nstart = (int)(pack >> 16);
  const float inv_v = rsqrtf((float)count + 1.0f);

  // ---- y1 slice = sum of both halves' partials (16 f32) ----
  fvec4 s1[4];
  {
    const unsigned int* p0 = y1G + ((size_t)(sg * 2 + 0) * NPG + v) * 16 + half * 8;
    const unsigned int* p1 = y1G + ((size_t)(sg * 2 + 1) * NPG + v) * 16 + half * 8;
#pragma unroll
    for (int w = 0; w < 8; ++w) {
      float2 fa = up2((int)p0[w]);
      float2 fb = up2((int)p1[w]);
      s1[w >> 1][(w & 1) * 2] = (fa.x + fb.x) * inv_v;
      s1[w >> 1][(w & 1) * 2 + 1] = (fa.y + fb.y) * inv_v;
    }
  }
  __syncthreads();  // sids staged
  // ---- publish 16 f16 (2 quads), key1 = (v<<1)|(v&1) ----
  const int myKey = (v << 1) | (v & 1);
  {
    ivec4 w0, w1;
    w0[0] = pkrtz(s1[0][0], s1[0][1]); w0[1] = pkrtz(s1[0][2], s1[0][3]);
    w0[2] = pkrtz(s1[1][0], s1[1][1]); w0[3] = pkrtz(s1[1][2], s1[1][3]);
    w1[0] = pkrtz(s1[2][0], s1[2][1]); w1[1] = pkrtz(s1[2][2], s1[2][3]);
    w1[2] = pkrtz(s1[3][0], s1[3][1]); w1[3] = pkrtz(s1[3][2], s1[3][3]);
    buf[myKey] = w0;
    buf[myKey ^ 1] = w1;
  }
  __syncthreads();

  // ---- gather 16 feats (unroll x2) ----
  {
    int e = nstart;
    const int end = nstart + count;
    for (; e + 2 <= end; e += 2) {
      const int la = sids[e], lb = sids[e + 1];
      const int Ka = (la << 1) | (la & 1), Kb = (lb << 1) | (lb & 1);
      const ivec4 a0_ = buf[Ka], a1_ = buf[Ka ^ 1];
      const ivec4 b0_ = buf[Kb], b1_ = buf[Kb ^ 1];
      ACCQ(s1[0], s1[1], a0_) ACCQ(s1[2], s1[3], a1_)
      ACCQ(s1[0], s1[1], b0_) ACCQ(s1[2], s1[3], b1_)
    }
    if (e < end) {
      const int la = sids[e];
      const int Ka = (la << 1) | (la & 1);
      const ivec4 a0_ = buf[Ka], a1_ = buf[Ka ^ 1];
      ACCQ(s1[0], s1[1], a0_) ACCQ(s1[2], s1[3], a1_)
    }
  }

  // ---- epilogue: h1_half = relu(s1*inv + b); hs1 slice; fold y2P = h1_half @ W2[half rows] ----
  const int slot = slot_of(v);
  const int hb = (side * BB + g) * 20;
  fvec4 y2P[4];
#pragma unroll
  for (int p = 0; p < 4; ++p) y2P[p] = fvec4{0.f, 0.f, 0.f, 0.f};
  {
    const fvec4* gb1v = reinterpret_cast<const fvec4*>(gb1 + half * 16);
    fvec4* hp = reinterpret_cast<fvec4*>(hs1 + ((size_t)hb + slot) * 32 + half * 16);
#pragma unroll
    for (int q = 0; q < 4; ++q) {
      fvec4 o = s1[q] * inv_v + gb1v[q];
#pragma unroll
      for (int j = 0; j < 4; ++j) o[j] = fmaxf(o[j], 0.f);
      if (slot >= 0) hp[q] = o;
#pragma unroll
      for (int j = 0; j < 4; ++j) {
        const float hf = o[j];
        const fvec4* wr = reinterpret_cast<const fvec4*>(gw2 + (size_t)(half * 16 + q * 4 + j) * 16);
#pragma unroll
        for (int p = 0; p < 4; ++p) y2P[p] += hf * wr[p];
      }
    }
  }
  {
    unsigned int* yp = y2G + ((size_t)(sg * 2 + half) * NPG + v) * 8;
#pragma unroll
    for (int w = 0; w < 8; ++w)
      yp[w] = (unsigned int)pkrtz(y2P[w >> 1][(w & 1) * 2], y2P[w >> 1][(w & 1) * 2 + 1]);
  }
}

// ================= kC: per (side,graph): L2 gather for sampled rows only =================
__global__ __launch_bounds__(512)
void kC(const float* __restrict__ gb2,
        const unsigned short* __restrict__ sidsG, const unsigned int* __restrict__ packG,
        const unsigned int* __restrict__ y2G, float* __restrict__ hs2) {
  __shared__ ivec4 buf[NPG * 2];          // 16 KB
  __shared__ unsigned short sids[EPG];    // 16 KB
  const int sg = blockIdx.x;
  const int side = sg >> 7, g = sg & 127;
  const int v = threadIdx.x;

  {
    const int* srcI = reinterpret_cast<const int*>(sidsG + sg * EPG);
    int* dstI = reinterpret_cast<int*>(sids);
    for (int k = v; k < EPG / 2; k += 512) dstI[k] = srcI[k];
  }
  const unsigned int pack = packG[sg * NPG + v];
  const int count = (int)(pack & 0xffffu);
  const float inv_v = rsqrtf((float)count + 1.0f);

  // y2 full = sum of both halves' partials; publish msg = y2*inv (16 f16)
  const int myKey = (v << 1) | (v & 1);
  {
    const unsigned int* p0 = y2G + ((size_t)(sg * 2 + 0) * NPG + v) * 8;
    const unsigned int* p1 = y2G + ((size_t)(sg * 2 + 1) * NPG + v) * 8;
    fvec4 y2[4];
#pragma unroll
    for (int w = 0; w < 8; ++w) {
      float2 fa = up2((int)p0[w]);
      float2 fb = up2((int)p1[w]);
      y2[w >> 1][(w & 1) * 2] = (fa.x + fb.x) * inv_v;
      y2[w >> 1][(w & 1) * 2 + 1] = (fa.y + fb.y) * inv_v;
    }
    ivec4 w0, w1;
    w0[0] = pkrtz(y2[0][0], y2[0][1]); w0[1] = pkrtz(y2[0][2], y2[0][3]);
    w0[2] = pkrtz(y2[1][0], y2[1][1]); w0[3] = pkrtz(y2[1][2], y2[1][3]);
    w1[0] = pkrtz(y2[2][0], y2[2][1]); w1[1] = pkrtz(y2[2][2], y2[2][3]);
    w1[2] = pkrtz(y2[3][0], y2[3][1]); w1[3] = pkrtz(y2[3][2], y2[3][3]);
    buf[myKey] = w0;
    buf[myKey ^ 1] = w1;
  }
  __syncthreads();

  if (v < 20) {
    const int n = c_srows[v];
    const unsigned int cp = packG[sg * NPG + n];
    const int ccount = (int)(cp & 0xffffu);
    const int cstart = (int)(cp >> 16);
    const float cinv = rsqrtf((float)ccount + 1.0f);
    const int ckey = (n << 1) | (n & 1);
    fvec4 s2[4];
#pragma unroll
    for (int q = 0; q < 4; ++q) s2[q] = fvec4{0.f, 0.f, 0.f, 0.f};
    {
      const ivec4 w0 = buf[ckey], w1 = buf[ckey ^ 1];
      ACCQ(s2[0], s2[1], w0) ACCQ(s2[2], s2[3], w1)
    }
    for (int e = cstart; e < cstart + ccount; ++e) {
      const int la = sids[e];
      const int Ka = (la << 1) | (la & 1);
      const ivec4 w0 = buf[Ka], w1 = buf[Ka ^ 1];
      ACCQ(s2[0], s2[1], w0) ACCQ(s2[2], s2[3], w1)
    }
    const int hb = (side * BB + g) * 20;
    const fvec4* gb2v = reinterpret_cast<const fvec4*>(gb2);
    fvec4* hp = reinterpret_cast<fvec4*>(hs2 + ((size_t)hb + v) * 16);
#pragma unroll
    for (int q = 0; q < 4; ++q) hp[q] = s2[q] * cinv + gb2v[q];
  }
}

// ---------------- head: sampled sim -> bilinear 10x10 -> conv3x3(1->8) -> MLP -> sigmoid ----------------
__global__ __launch_bounds__(256) void k_head(const float* __restrict__ hs0, const float* __restrict__ hs1,
                                              const float* __restrict__ hs2,
                                              const float* __restrict__ cw0, const float* __restrict__ cb0,
                                              const float* __restrict__ cw1, const float* __restrict__ cb1,
                                              const float* __restrict__ cw2, const float* __restrict__ cb2,
                                              const float* __restrict__ mw0, const float* __restrict__ mb0,
                                              const float* __restrict__ mw1, const float* __restrict__ mb1,
                                              const float* __restrict__ mw2, const float* __restrict__ mb2,
                                              const float* __restrict__ mw3, const float* __restrict__ mb3,
                                              const float* __restrict__ mw4, const float* __restrict__ mb4,
                                              const float* __restrict__ sw, const float* __restrict__ sb,
                                              float* __restrict__ out) {
  __shared__ float hi[2240];  // 20*64 + 20*32 + 20*16
  __shared__ float hj[2240];
  __shared__ float sim[400];
  __shared__ float simr[100];
  __shared__ float feat[2400];
  __shared__ float red[256];
  __shared__ float mbuf[60];
  const int b = blockIdx.x, t = threadIdx.x;

  for (int k = t; k < 1280; k += 256) {
    hi[k] = hs0[(size_t)(0 * BB + b) * 1280 + k];
    hj[k] = hs0[(size_t)(1 * BB + b) * 1280 + k];
  }
  for (int k = t; k < 640; k += 256) {
    hi[1280 + k] = hs1[(size_t)(0 * BB + b) * 640 + k];
    hj[1280 + k] = hs1[(size_t)(1 * BB + b) * 640 + k];
  }
  for (int k = t; k < 320; k += 256) {
    hi[1920 + k] = hs2[(size_t)(0 * BB + b) * 320 + k];
    hj[1920 + k] = hs2[(size_t)(1 * BB + b) * 320 + k];
  }
  __syncthreads();

  const int Fs[3] = {64, 32, 16};
  const int HOFF[3] = {0, 1280, 1920};
  const float* CW[3] = {cw0, cw1, cw2};
  const float* CB[3] = {cb0, cb1, cb2};

  for (int li = 0; li < 3; ++li) {
    const int F = Fs[li];
    const float* Hi = hi + HOFF[li];
    const float* Hj = hj + HOFF[li];
    for (int p = t; p < 400; p += 256) {
      int r = p / 20, cq = p % 20;
      float a = 0.0f;
      for (int d = 0; d < F; ++d) a += Hi[r * F + d] * Hj[cq * F + d];
      sim[p] = a;
    }
    __syncthreads();
    if (t < 100) {
      int oy = t / 10, ox = t % 10;
      float cy = (oy + 0.5f) * (512.0f / 10.0f) - 0.5f;
      float cx = (ox + 0.5f) * (512.0f / 10.0f) - 0.5f;
      float fy = cy - floorf(cy);
      float fx = cx - floorf(cx);
      int r0 = 2 * oy, c0 = 2 * ox;
      float s00 = sim[r0 * 20 + c0], s01 = sim[r0 * 20 + c0 + 1];
      float s10 = sim[(r0 + 1) * 20 + c0], s11 = sim[(r0 + 1) * 20 + c0 + 1];
      simr[t] = (1.0f - fy) * ((1.0f - fx) * s00 + fx * s01) + fy * ((1.0f - fx) * s10 + fx * s11);
    }
    __syncthreads();
    const float* cw = CW[li];
    const float* cb = CB[li];
    for (int idx = t; idx < 800; idx += 256) {
      int cch = idx / 100, rem = idx % 100, y = rem / 10, x = rem % 10;
      float a = cb[cch];
#pragma unroll
      for (int ky = 0; ky < 3; ++ky) {
#pragma unroll
        for (int kx = 0; kx < 3; ++kx) {
          int iy = y + ky - 1, ix = x + kx - 1;
          if (iy >= 0 && iy < 10 && ix >= 0 && ix < 10)
            a += cw[cch * 9 + ky * 3 + kx] * simr[iy * 10 + ix];
        }
      }
      feat[li * 800 + idx] = fmaxf(a, 0.0f);
    }
    __syncthreads();
  }

  // MLP0: 2400 -> 32, 8 partial sums per output
  {
    int f = t & 31, part = t >> 5;
    float a = 0.0f;
    int k0 = part * 300;
    for (int k = k0; k < k0 + 300; ++k) a += feat[k] * mw0[k * 32 + f];
    red[t] = a;
    __syncthreads();
    if (t < 32) {
      float s = mb0[t];
#pragma unroll
      for (int p = 0; p < 8; ++p) s += red[p * 32 + t];
      mbuf[t] = fmaxf(s, 0.0f);
    }
    __syncthreads();
  }
  if (t < 16) {
    float s = mb1[t];
    for (int k = 0; k < 32; ++k) s += mbuf[k] * mw1[k * 16 + t];
    mbuf[32 + t] = fmaxf(s, 0.0f);
  }
  __syncthreads();
  if (t < 8) {
    float s = mb2[t];
    for (int k = 0; k < 16; ++k) s += mbuf[32 + k] * mw2[k * 8 + t];
    mbuf[48 + t] = fmaxf(s, 0.0f);
  }
  __syncthreads();
  if (t < 4) {
    float s = mb3[t];
    for (int k = 0; k < 8; ++k) s += mbuf[48 + k] * mw3[k * 4 + t];
    mbuf[56 + t] = fmaxf(s, 0.0f);
  }
  __syncthreads();
  if (t == 0) {
    float s = mb4[0];
    for (int k = 0; k < 4; ++k) s += mbuf[56 + k] * mw4[k];
    s = fmaxf(s, 0.0f);
    float z = s * sw[0] + sb[0];
    out[b] = 1.0f / (1.0f + expf(-z));
  }
}

extern "C" void kernel_launch(void* const* d_in, const int* in_sizes, int n_in,
                              void* d_out, int out_size, void* d_ws, size_t ws_size,
                              hipStream_t stream) {
  (void)in_sizes; (void)n_in; (void)out_size; (void)ws_size;
  const float* x_i = (const float*)d_in[0];
  const float* x_j = (const float*)d_in[1];
  const float* gw0 = (const float*)d_in[2];
  const float* gb0 = (const float*)d_in[3];
  const float* gw1 = (const float*)d_in[4];
  const float* gb1 = (const float*)d_in[5];
  const float* gw2 = (const float*)d_in[6];
  const float* gb2 = (const float*)d_in[7];
  const float* cw0 = (const float*)d_in[8];
  const float* cb0 = (const float*)d_in[9];
  const float* cw1 = (const float*)d_in[10];
  const float* cb1 = (const float*)d_in[11];
  const float* cw2 = (const float*)d_in[12];
  const float* cb2 = (const float*)d_in[13];
  const float* mw0 = (const float*)d_in[14];
  const float* mb0 = (const float*)d_in[15];
  const float* mw1 = (const float*)d_in[16];
  const float* mb1 = (const float*)d_in[17];
  const float* mw2 = (const float*)d_in[18];
  const float* mb2 = (const float*)d_in[19];
  const float* mw3 = (const float*)d_in[20];
  const float* mb3 = (const float*)d_in[21];
  const float* mw4 = (const float*)d_in[22];
  const float* mb4 = (const float*)d_in[23];
  const float* scw = (const float*)d_in[24];
  const float* scb = (const float*)d_in[25];
  const int* ei = (const int*)d_in[26];
  const int* ej = (const int*)d_in[27];
  float* out = (float*)d_out;

  char* p = (char*)d_ws;
  auto take = [&](size_t bytes) {
    char* r = p;
    p += (bytes + 255) & ~(size_t)255;
    return r;
  };
  float* hs0 = (float*)take((size_t)2 * BB * 20 * 64 * 4);
  float* hs1 = (float*)take((size_t)2 * BB * 20 * 32 * 4);
  float* hs2 = (float*)take((size_t)2 * BB * 20 * 16 * 4);
  unsigned short* sidsG = (unsigned short*)take((size_t)2 * BB * EPG * 2);
  unsigned int* packG = (unsigned int*)take((size_t)2 * BB * NPG * 4);
  unsigned int* y1G = (unsigned int*)take((size_t)2 * BB * 2 * NPG * 16 * 4);
  unsigned int* y2G = (unsigned int*)take((size_t)2 * BB * 2 * NPG * 8 * 4);

  kA<<<2 * BB * 2, 512, 0, stream>>>(x_i, x_j, gw0, gb0, gw1, ei, ej,
                                     sidsG, packG, hs0, y1G);
  kB<<<2 * BB * 2, 512, 0, stream>>>(gb1, gw2, sidsG, packG, y1G, hs1, y2G);
  kC<<<2 * BB, 512, 0, stream>>>(gb2, sidsG, packG, y2G, hs2);
  k_head<<<BB, 256, 0, stream>>>(hs0, hs1, hs2, cw0, cb0, cw1, cb1, cw2, cb2,
                                 mw0, mb0, mw1, mb1, mw2, mb2, mw3, mb3, mw4, mb4,
                                 scw, scb, out);
}